// Round 1
// 430.311 us; speedup vs baseline: 1.0138x; 1.0138x over previous
//
#include <hip/hip_runtime.h>
#include <hip/hip_bf16.h>

// GQA fwd: B=2, S=2048, D_IN=2048, H=16, KV=4, Dh=128, GROUP=4, scale=1/16.
// Inputs fp32, output fp32. Intermediates bf16.
// cvt(x)+tcvt(W) -> m97-style bf16 GEMMs (q; fused k|v) -> fused rmsrope(q,k)
// -> vtrans -> MFMA flash attn (64-row q-tiles, double-buffered gl16 staging,
// XOR-swizzled LDS, 1-barrier/tile pipeline, LPT block order) -> gemm(out, f32).

using u16 = unsigned short;
using u32 = unsigned int;

constexpr int Ss  = 2048;
constexpr int Hh  = 16;
constexpr int KVH = 4;

typedef __attribute__((ext_vector_type(8))) short bf16x8;
typedef __attribute__((ext_vector_type(4))) float f32x4;

__device__ inline float b2f(u16 v)  { return __uint_as_float(((u32)v) << 16); }
__device__ inline u16 f2bf(float x) {
  u32 u = __float_as_uint(x);
  return (u16)((u + 0x7fffu + ((u >> 16) & 1u)) >> 16);
}

typedef const __attribute__((address_space(1))) unsigned int gas_u32;
typedef __attribute__((address_space(3))) unsigned int las_u32;
__device__ inline void gl16(const void* g, void* l) {
  __builtin_amdgcn_global_load_lds((gas_u32*)g, (las_u32*)l, 16, 0, 0);
}

// ---------------------------------------------------------------------------
__global__ __launch_bounds__(256) void cvt_bf16(const float* __restrict__ in,
                                                u16* __restrict__ out, int n4) {
  int i = blockIdx.x * 256 + threadIdx.x;
  if (i < n4) {
    float4 f = reinterpret_cast<const float4*>(in)[i];
    ushort4 o;
    o.x = f2bf(f.x); o.y = f2bf(f.y); o.z = f2bf(f.z); o.w = f2bf(f.w);
    reinterpret_cast<ushort4*>(out)[i] = o;
  }
}

// ---------------------------------------------------------------------------
// W [K][N] fp32 -> W^T [N][K] bf16, 64x64 LDS tiles
// ---------------------------------------------------------------------------
__global__ __launch_bounds__(256) void tcvt(const float* __restrict__ in,
                                            u16* __restrict__ out, int N, int K) {
  __shared__ u16 T[64][66];
  const int k0 = blockIdx.x * 64, n0 = blockIdx.y * 64;
  const int c = threadIdx.x & 63, rb = threadIdx.x >> 6;
#pragma unroll
  for (int p = 0; p < 16; p++) {
    int r = p * 4 + rb;
    T[c][r] = f2bf(in[(size_t)(k0 + r) * N + n0 + c]);
  }
  __syncthreads();
#pragma unroll
  for (int p = 0; p < 16; p++) {
    int nr = p * 4 + rb;
    out[(size_t)(n0 + nr) * K + k0 + c] = T[nr][c];
  }
}

// ---------------------------------------------------------------------------
// v half of kv [4096 tok][1024] bf16 -> vT [(b*4+kvh)][128 d][2048 s]
// ---------------------------------------------------------------------------
__global__ __launch_bounds__(256) void vtrans(const u16* __restrict__ kv,
                                              u16* __restrict__ vT) {
  __shared__ u16 T[64][66];
  const int s0 = blockIdx.x * 64, d0 = blockIdx.y * 64, z = blockIdx.z;
  const int b = z >> 2, kvh = z & 3;
  const int c = threadIdx.x & 63, rb = threadIdx.x >> 6;
#pragma unroll
  for (int p = 0; p < 16; p++) {
    int r = p * 4 + rb;
    T[c][r] = kv[(size_t)(b * Ss + s0 + r) * 1024 + 512 + kvh * 128 + d0 + c];
  }
  __syncthreads();
#pragma unroll
  for (int p = 0; p < 16; p++) {
    int dr = p * 4 + rb;
    vT[((size_t)z * 128 + d0 + dr) * Ss + s0 + c] = T[dr][c];
  }
}

// ---------------------------------------------------------------------------
// C[M x N] = A[M x K](bf16) @ Bt[N x K](bf16)^T.  m97 structure.
// ---------------------------------------------------------------------------
template <int OUT_F32>
__global__ __launch_bounds__(256) void gemm_bt(const u16* __restrict__ A,
                                               const u16* __restrict__ Bt,
                                               void* __restrict__ C,
                                               int N, int K) {
  __shared__ u16 As[128 * 64];
  __shared__ u16 Bs[128 * 64];
  const int t = threadIdx.x, w = t >> 6, lane = t & 63;
  const int lrow = lane & 15, quad = lane >> 4;
  const int wm = w & 1, wn = w >> 1;
  const int m0 = blockIdx.x * 128, n0 = blockIdx.y * 128;

  f32x4 acc[4][4];
#pragma unroll
  for (int i = 0; i < 4; i++)
#pragma unroll
    for (int j = 0; j < 4; j++) acc[i][j] = (f32x4)0.f;

  const int srow = t >> 3;
  const int scol = (t & 7) * 8;

  for (int k0 = 0; k0 < K; k0 += 64) {
#pragma unroll
    for (int c = 0; c < 4; c++) {
      gl16(A + (size_t)(m0 + c * 32 + srow) * K + k0 + scol,
           (char*)As + c * 4096 + t * 16);
      gl16(Bt + (size_t)(n0 + c * 32 + srow) * K + k0 + scol,
           (char*)Bs + c * 4096 + t * 16);
    }
    __syncthreads();
#pragma unroll
    for (int kc = 0; kc < 2; kc++) {
      bf16x8 af[4], bfr[4];
#pragma unroll
      for (int i = 0; i < 4; i++) {
        af[i] = *reinterpret_cast<const bf16x8*>(
            &As[(wm * 64 + i * 16 + lrow) * 64 + kc * 32 + quad * 8]);
        bfr[i] = *reinterpret_cast<const bf16x8*>(
            &Bs[(wn * 64 + i * 16 + lrow) * 64 + kc * 32 + quad * 8]);
      }
#pragma unroll
      for (int mi = 0; mi < 4; mi++)
#pragma unroll
        for (int ni = 0; ni < 4; ni++)
          acc[mi][ni] =
              __builtin_amdgcn_mfma_f32_16x16x32_bf16(af[mi], bfr[ni], acc[mi][ni], 0, 0, 0);
    }
    __syncthreads();
  }

#pragma unroll
  for (int mi = 0; mi < 4; mi++)
#pragma unroll
    for (int ni = 0; ni < 4; ni++)
#pragma unroll
      for (int r = 0; r < 4; r++) {
        int row = m0 + wm * 64 + mi * 16 + quad * 4 + r;
        int col = n0 + wn * 64 + ni * 16 + lrow;
        if (OUT_F32)
          reinterpret_cast<float*>(C)[(size_t)row * N + col] = acc[mi][ni][r];
        else
          reinterpret_cast<u16*>(C)[(size_t)row * N + col] = f2bf(acc[mi][ni][r]);
      }
}

// ---------------------------------------------------------------------------
// Fused RMSNorm + RoPE for q and k. 20 vectors/token: j<16 -> q head j
// (stride 2048, mult 1/16), j>=16 -> k head j-16 in kv buffer (stride 1024).
// One wave per vector.
// ---------------------------------------------------------------------------
__global__ __launch_bounds__(256) void rmsrope2(u16* __restrict__ qbuf,
                                                u16* __restrict__ kvb,
                                                const float* __restrict__ qsc,
                                                const float* __restrict__ ksc,
                                                const float* __restrict__ cosb,
                                                const float* __restrict__ sinb) {
  const int w = threadIdx.x >> 6, lane = threadIdx.x & 63;
  const int vi = blockIdx.x * 4 + w;
  const int tok = vi / 20, j = vi - tok * 20;
  const int s = tok & (Ss - 1);
  const bool isq = j < 16;
  u16* p = isq ? (qbuf + (size_t)tok * 2048 + j * 128)
               : (kvb + (size_t)tok * 1024 + (j - 16) * 128);
  const float* scale = isq ? qsc : ksc;
  const float mult = isq ? 0.0625f : 1.0f;
  float e0 = b2f(p[lane]), e1 = b2f(p[lane + 64]);
  float ss = e0 * e0 + e1 * e1;
#pragma unroll
  for (int off = 32; off > 0; off >>= 1) ss += __shfl_xor(ss, off);
  float rr = rsqrtf(ss * (1.0f / 128.0f) + 1e-6f);
  float x0 = e0 * rr * scale[lane];
  float x1 = e1 * rr * scale[lane + 64];
  float c0 = cosb[s * 128 + lane], c1 = cosb[s * 128 + 64 + lane];
  float sn0 = sinb[s * 128 + lane], sn1 = sinb[s * 128 + 64 + lane];
  p[lane]      = f2bf((x0 * c0 - x1 * sn0) * mult);
  p[lane + 64] = f2bf((x1 * c1 + x0 * sn1) * mult);
}

// ---------------------------------------------------------------------------
// MFMA flash attention (causal, GQA). One 64-row q-tile per block, 4 waves x
// 16 q-rows. Grid (32,16,2)=1024 blocks, qt reversed (longest-first / LPT).
// Double-buffered K/V staging via global_load_lds (zero staging registers),
// XOR-swizzled chunks (both-sides involution: pre-swizzled global source ->
// linear LDS dest; same XOR applied on ds_read_b128 address). One barrier
// per tile: issue next-tile gl16s, compute current, __syncthreads (its
// implicit vmcnt(0) drains the in-flight loads AFTER compute hides them).
// S^T = K.Q^T; softmax per (lane&15); P packed b64 to LDS; PV = P x V^T.
// LDS: 2*16KB K + 2*16KB V + 9KB P = 73KB -> 2 blocks/CU.
// ---------------------------------------------------------------------------
__global__ __launch_bounds__(256, 2) void attn_mfma(const u16* __restrict__ qb,
                                                    const u16* __restrict__ kv,
                                                    const u16* __restrict__ vT,
                                                    u16* __restrict__ ctx) {
  __shared__ u16 Ks[2][64 * 128];   // [key][d] linear, chunk^=(key&7)
  __shared__ u16 Vs[2][128 * 64];   // [d][key] linear, chunk^=(d&7)
  __shared__ u16 Ps[4][16 * 72];    // per-wave P [q][key] stride 72
  const int qt = (int)gridDim.x - 1 - (int)blockIdx.x;  // LPT: longest first
  const int h = blockIdx.y, b = blockIdx.z;
  const int t = threadIdx.x, w = t >> 6, lane = t & 63;
  const int lrow = lane & 15, quad = lane >> 4;
  const int kvh = h >> 2;
  const int qw = qt * 64 + w * 16;   // wave's first q row

  const u16* kbase = kv + (size_t)b * Ss * 1024 + kvh * 128;   // key stride 1024
  const u16* vbase = vT + (size_t)(b * KVH + kvh) * 128 * Ss;  // + d*Ss + s

  // staging decomposition: thread t stages LDS chunk (p*256+t) each p.
  // K: row p*16 + (t>>4), chunk t&15; V: row p*32 + (t>>3), chunk t&7.
  // Global source chunk pre-XORed with (row&7) (p-independent: 16p%8==0).
  const int kr  = t >> 4;
  const int kco = ((t & 15) ^ (kr & 7)) * 8;   // u16 offset within K row
  const int vr  = t >> 3;
  const int vco = ((t & 7) ^ (vr & 7)) * 8;    // u16 offset within V row
  const int sw8 = (lrow & 7) << 3;             // read-side XOR (u16 units)

  // stationary Q B-frags: qf[c] -> Q[qw+lrow][c*32+quad*8 ..+7]
  bf16x8 qf[4];
#pragma unroll
  for (int c = 0; c < 4; c++)
    qf[c] = *reinterpret_cast<const bf16x8*>(
        qb + ((size_t)(b * Ss + qw + lrow) * Hh + h) * 128 + c * 32 + quad * 8);

  f32x4 o[8];
#pragma unroll
  for (int n = 0; n < 8; n++) o[n] = (f32x4)0.f;
  float mx = -1e30f, ls = 0.f;

  const int ntile = qt + 1;

  // prologue: stage tile 0 into buffer 0
#pragma unroll
  for (int p = 0; p < 4; p++) {
    gl16(kbase + (size_t)(p * 16 + kr) * 1024 + kco,
         (char*)Ks[0] + (p * 256 + t) * 16);
    gl16(vbase + (size_t)(p * 32 + vr) * Ss + vco,
         (char*)Vs[0] + (p * 256 + t) * 16);
  }
  __syncthreads();

  int cur = 0;
  for (int kt = 0; kt < ntile; kt++) {
    const int kb0 = kt * 64;
    // issue next tile's loads into the other buffer (hidden under compute)
    if (kt + 1 < ntile) {
      const int nb0 = kb0 + 64;
#pragma unroll
      for (int p = 0; p < 4; p++) {
        gl16(kbase + (size_t)(nb0 + p * 16 + kr) * 1024 + kco,
             (char*)Ks[cur ^ 1] + (p * 256 + t) * 16);
        gl16(vbase + (size_t)(p * 32 + vr) * Ss + nb0 + vco,
             (char*)Vs[cur ^ 1] + (p * 256 + t) * 16);
      }
    }

    // S^T[key][q]: st[mt], key = kb0+mt*16+quad*4+r, q = qw+lrow
    f32x4 st[4];
#pragma unroll
    for (int mt = 0; mt < 4; mt++) st[mt] = (f32x4)0.f;
#pragma unroll
    for (int c = 0; c < 4; c++) {
      bf16x8 kf[4];
#pragma unroll
      for (int mt = 0; mt < 4; mt++)
        kf[mt] = *reinterpret_cast<const bf16x8*>(
            &Ks[cur][(mt * 16 + lrow) * 128 + ((((c * 4 + quad) << 3)) ^ sw8)]);
      __builtin_amdgcn_s_setprio(1);
#pragma unroll
      for (int mt = 0; mt < 4; mt++)
        st[mt] = __builtin_amdgcn_mfma_f32_16x16x32_bf16(kf[mt], qf[c], st[mt], 0, 0, 0);
      __builtin_amdgcn_s_setprio(0);
    }
    // causal mask near diagonal
    if (kb0 + 63 > qw) {
#pragma unroll
      for (int mt = 0; mt < 4; mt++) {
        int kg = kb0 + mt * 16 + quad * 4;
        int qg = qw + lrow;
#pragma unroll
        for (int r = 0; r < 4; r++)
          st[mt][r] = (kg + r > qg) ? -1e30f : st[mt][r];
      }
    }
    // online softmax (state per q = lrow, replicated over quads)
    f32x4 m4;
#pragma unroll
    for (int r = 0; r < 4; r++)
      m4[r] = fmaxf(fmaxf(st[0][r], st[1][r]), fmaxf(st[2][r], st[3][r]));
    float tm = fmaxf(fmaxf(m4[0], m4[1]), fmaxf(m4[2], m4[3]));
    tm = fmaxf(tm, __shfl_xor(tm, 16));
    tm = fmaxf(tm, __shfl_xor(tm, 32));
    float mn = fmaxf(mx, tm);
    float alpha = __expf(mx - mn);
    mx = mn;
    float tsum = 0.f;
#pragma unroll
    for (int mt = 0; mt < 4; mt++)
#pragma unroll
      for (int r = 0; r < 4; r++) {
        float pv = __expf(st[mt][r] - mn);
        st[mt][r] = pv;
        tsum += pv;
      }
    tsum += __shfl_xor(tsum, 16);
    tsum += __shfl_xor(tsum, 32);
    ls = ls * alpha + tsum;
    // P -> per-wave LDS (packed 4 consecutive keys, b64)
#pragma unroll
    for (int mt = 0; mt < 4; mt++) {
      ushort4 pk;
      pk.x = f2bf(st[mt][0]);
      pk.y = f2bf(st[mt][1]);
      pk.z = f2bf(st[mt][2]);
      pk.w = f2bf(st[mt][3]);
      *reinterpret_cast<ushort4*>(&Ps[w][lrow * 72 + mt * 16 + quad * 4]) = pk;
    }
    // rescale O (row r of o[n] is q = quad*4+r; alpha held at lane q&15)
    f32x4 av;
#pragma unroll
    for (int r = 0; r < 4; r++) av[r] = __shfl(alpha, quad * 4 + r);
#pragma unroll
    for (int n = 0; n < 8; n++) o[n] *= av;
    // PV
#pragma unroll
    for (int c2 = 0; c2 < 2; c2++) {
      bf16x8 pf = *reinterpret_cast<const bf16x8*>(
          &Ps[w][lrow * 72 + c2 * 32 + quad * 8]);
      __builtin_amdgcn_s_setprio(1);
#pragma unroll
      for (int n = 0; n < 8; n++) {
        bf16x8 vf = *reinterpret_cast<const bf16x8*>(
            &Vs[cur][(n * 16 + lrow) * 64 + ((((c2 * 4 + quad) << 3)) ^ sw8)]);
        o[n] = __builtin_amdgcn_mfma_f32_16x16x32_bf16(pf, vf, o[n], 0, 0, 0);
      }
      __builtin_amdgcn_s_setprio(0);
    }

    // one barrier per tile: implicit vmcnt(0)+lgkmcnt(0) drains the gl16s
    // issued at the top of this iteration (they had the compute to land).
    __syncthreads();
    cur ^= 1;
  }

  // epilogue: divide by l (per-row via shuffle), write ctx bf16
  f32x4 linv;
#pragma unroll
  for (int r = 0; r < 4; r++) linv[r] = 1.0f / __shfl(ls, quad * 4 + r);
#pragma unroll
  for (int n = 0; n < 8; n++)
#pragma unroll
    for (int r = 0; r < 4; r++) {
      int q = qw + quad * 4 + r;
      ctx[((size_t)(b * Ss + q) * Hh + h) * 128 + n * 16 + lrow] = f2bf(o[n][r] * linv[r]);
    }
}

// ---------------------------------------------------------------------------
extern "C" void kernel_launch(void* const* d_in, const int* in_sizes, int n_in,
                              void* d_out, int out_size, void* d_ws, size_t ws_size,
                              hipStream_t stream) {
  const float* x    = (const float*)d_in[0];
  // d_in[1] = mask (unused; causal handled analytically)
  const float* cosb = (const float*)d_in[2];
  const float* sinb = (const float*)d_in[3];
  const float* Wq   = (const float*)d_in[4];
  const float* Wk   = (const float*)d_in[5];
  const float* Wv   = (const float*)d_in[6];
  const float* Wo   = (const float*)d_in[7];
  const float* qsc  = (const float*)d_in[8];
  const float* ksc  = (const float*)d_in[9];

  const int M = 2 * Ss;  // 4096 tokens
  // workspace (u16 elems); ctxb aliases xb (xb dead after kv gemm)
  u16* xb   = (u16*)d_ws;                      // 8,388,608
  u16* ctxb = xb;                              // alias
  u16* Wt   = xb + (size_t)8388608;            // 4,194,304 (reused per-W)
  u16* qbuf = Wt + (size_t)4194304;            // 8,388,608
  u16* kvb  = qbuf + (size_t)8388608;          // 4,194,304  [tok][1024] k|v
  u16* vTb  = kvb + (size_t)4194304;           // 2,097,152  [(b,kvh)][128][2048]

  cvt_bf16<<<8192, 256, 0, stream>>>(x, xb, 2097152);

  tcvt<<<dim3(32, 32), 256, 0, stream>>>(Wq, Wt, 2048, 2048);
  gemm_bt<0><<<dim3(32, 16), 256, 0, stream>>>(xb, Wt, qbuf, 2048, 2048);

  tcvt<<<dim3(32, 8), 256, 0, stream>>>(Wk, Wt, 512, 2048);                       // rows 0..511
  tcvt<<<dim3(32, 8), 256, 0, stream>>>(Wv, Wt + (size_t)512 * 2048, 512, 2048);  // rows 512..1023
  gemm_bt<0><<<dim3(32, 8), 256, 0, stream>>>(xb, Wt, kvb, 1024, 2048);

  rmsrope2<<<(M * 20) / 4, 256, 0, stream>>>(qbuf, kvb, qsc, ksc, cosb, sinb);

  vtrans<<<dim3(32, 2, 8), 256, 0, stream>>>(kvb, vTb);

  attn_mfma<<<dim3(32, Hh, 2), 256, 0, stream>>>(qbuf, kvb, vTb, ctxb);

  tcvt<<<dim3(32, 32), 256, 0, stream>>>(Wo, Wt, 2048, 2048);
  gemm_bt<1><<<dim3(32, 16), 256, 0, stream>>>(ctxb, Wt, d_out, 2048, 2048);
}

// Round 2
// 387.958 us; speedup vs baseline: 1.1245x; 1.1092x over previous
//
#include <hip/hip_runtime.h>
#include <hip/hip_bf16.h>

// GQA fwd: B=2, S=2048, D_IN=2048, H=16, KV=4, Dh=128, GROUP=4, scale=1/16.
// Inputs fp32, output fp32. Intermediates bf16.
// cvt(x)+tcvt(W) -> m97-style bf16 GEMMs (q; fused k|v) -> fused rmsrope(q,k)
// -> vtrans -> MFMA flash attn (128-row q-tiles, 32 q/wave, double-buffered
// gl16 staging, XOR-swizzled LDS, transposed PV (lane-local softmax state),
// complementary-LPT block pairing) -> gemm(out, f32).

using u16 = unsigned short;
using u32 = unsigned int;

constexpr int Ss  = 2048;
constexpr int Hh  = 16;
constexpr int KVH = 4;

typedef __attribute__((ext_vector_type(8))) short bf16x8;
typedef __attribute__((ext_vector_type(4))) float f32x4;

__device__ inline float b2f(u16 v)  { return __uint_as_float(((u32)v) << 16); }
__device__ inline u16 f2bf(float x) {
  u32 u = __float_as_uint(x);
  return (u16)((u + 0x7fffu + ((u >> 16) & 1u)) >> 16);
}

typedef const __attribute__((address_space(1))) unsigned int gas_u32;
typedef __attribute__((address_space(3))) unsigned int las_u32;
__device__ inline void gl16(const void* g, void* l) {
  __builtin_amdgcn_global_load_lds((gas_u32*)g, (las_u32*)l, 16, 0, 0);
}

// ---------------------------------------------------------------------------
__global__ __launch_bounds__(256) void cvt_bf16(const float* __restrict__ in,
                                                u16* __restrict__ out, int n4) {
  int i = blockIdx.x * 256 + threadIdx.x;
  if (i < n4) {
    float4 f = reinterpret_cast<const float4*>(in)[i];
    ushort4 o;
    o.x = f2bf(f.x); o.y = f2bf(f.y); o.z = f2bf(f.z); o.w = f2bf(f.w);
    reinterpret_cast<ushort4*>(out)[i] = o;
  }
}

// ---------------------------------------------------------------------------
// W [K][N] fp32 -> W^T [N][K] bf16, 64x64 LDS tiles
// ---------------------------------------------------------------------------
__global__ __launch_bounds__(256) void tcvt(const float* __restrict__ in,
                                            u16* __restrict__ out, int N, int K) {
  __shared__ u16 T[64][66];
  const int k0 = blockIdx.x * 64, n0 = blockIdx.y * 64;
  const int c = threadIdx.x & 63, rb = threadIdx.x >> 6;
#pragma unroll
  for (int p = 0; p < 16; p++) {
    int r = p * 4 + rb;
    T[c][r] = f2bf(in[(size_t)(k0 + r) * N + n0 + c]);
  }
  __syncthreads();
#pragma unroll
  for (int p = 0; p < 16; p++) {
    int nr = p * 4 + rb;
    out[(size_t)(n0 + nr) * K + k0 + c] = T[nr][c];
  }
}

// ---------------------------------------------------------------------------
// v half of kv [4096 tok][1024] bf16 -> vT [(b*4+kvh)][128 d][2048 s]
// ---------------------------------------------------------------------------
__global__ __launch_bounds__(256) void vtrans(const u16* __restrict__ kv,
                                              u16* __restrict__ vT) {
  __shared__ u16 T[64][66];
  const int s0 = blockIdx.x * 64, d0 = blockIdx.y * 64, z = blockIdx.z;
  const int b = z >> 2, kvh = z & 3;
  const int c = threadIdx.x & 63, rb = threadIdx.x >> 6;
#pragma unroll
  for (int p = 0; p < 16; p++) {
    int r = p * 4 + rb;
    T[c][r] = kv[(size_t)(b * Ss + s0 + r) * 1024 + 512 + kvh * 128 + d0 + c];
  }
  __syncthreads();
#pragma unroll
  for (int p = 0; p < 16; p++) {
    int dr = p * 4 + rb;
    vT[((size_t)z * 128 + d0 + dr) * Ss + s0 + c] = T[dr][c];
  }
}

// ---------------------------------------------------------------------------
// C[M x N] = A[M x K](bf16) @ Bt[N x K](bf16)^T.  m97 structure.
// ---------------------------------------------------------------------------
template <int OUT_F32>
__global__ __launch_bounds__(256) void gemm_bt(const u16* __restrict__ A,
                                               const u16* __restrict__ Bt,
                                               void* __restrict__ C,
                                               int N, int K) {
  __shared__ u16 As[128 * 64];
  __shared__ u16 Bs[128 * 64];
  const int t = threadIdx.x, w = t >> 6, lane = t & 63;
  const int lrow = lane & 15, quad = lane >> 4;
  const int wm = w & 1, wn = w >> 1;
  const int m0 = blockIdx.x * 128, n0 = blockIdx.y * 128;

  f32x4 acc[4][4];
#pragma unroll
  for (int i = 0; i < 4; i++)
#pragma unroll
    for (int j = 0; j < 4; j++) acc[i][j] = (f32x4)0.f;

  const int srow = t >> 3;
  const int scol = (t & 7) * 8;

  for (int k0 = 0; k0 < K; k0 += 64) {
#pragma unroll
    for (int c = 0; c < 4; c++) {
      gl16(A + (size_t)(m0 + c * 32 + srow) * K + k0 + scol,
           (char*)As + c * 4096 + t * 16);
      gl16(Bt + (size_t)(n0 + c * 32 + srow) * K + k0 + scol,
           (char*)Bs + c * 4096 + t * 16);
    }
    __syncthreads();
#pragma unroll
    for (int kc = 0; kc < 2; kc++) {
      bf16x8 af[4], bfr[4];
#pragma unroll
      for (int i = 0; i < 4; i++) {
        af[i] = *reinterpret_cast<const bf16x8*>(
            &As[(wm * 64 + i * 16 + lrow) * 64 + kc * 32 + quad * 8]);
        bfr[i] = *reinterpret_cast<const bf16x8*>(
            &Bs[(wn * 64 + i * 16 + lrow) * 64 + kc * 32 + quad * 8]);
      }
#pragma unroll
      for (int mi = 0; mi < 4; mi++)
#pragma unroll
        for (int ni = 0; ni < 4; ni++)
          acc[mi][ni] =
              __builtin_amdgcn_mfma_f32_16x16x32_bf16(af[mi], bfr[ni], acc[mi][ni], 0, 0, 0);
    }
    __syncthreads();
  }

#pragma unroll
  for (int mi = 0; mi < 4; mi++)
#pragma unroll
    for (int ni = 0; ni < 4; ni++)
#pragma unroll
      for (int r = 0; r < 4; r++) {
        int row = m0 + wm * 64 + mi * 16 + quad * 4 + r;
        int col = n0 + wn * 64 + ni * 16 + lrow;
        if (OUT_F32)
          reinterpret_cast<float*>(C)[(size_t)row * N + col] = acc[mi][ni][r];
        else
          reinterpret_cast<u16*>(C)[(size_t)row * N + col] = f2bf(acc[mi][ni][r]);
      }
}

// ---------------------------------------------------------------------------
// Fused RMSNorm + RoPE for q and k. 20 vectors/token: j<16 -> q head j
// (stride 2048, mult 1/16), j>=16 -> k head j-16 in kv buffer (stride 1024).
// One wave per vector.
// ---------------------------------------------------------------------------
__global__ __launch_bounds__(256) void rmsrope2(u16* __restrict__ qbuf,
                                                u16* __restrict__ kvb,
                                                const float* __restrict__ qsc,
                                                const float* __restrict__ ksc,
                                                const float* __restrict__ cosb,
                                                const float* __restrict__ sinb) {
  const int w = threadIdx.x >> 6, lane = threadIdx.x & 63;
  const int vi = blockIdx.x * 4 + w;
  const int tok = vi / 20, j = vi - tok * 20;
  const int s = tok & (Ss - 1);
  const bool isq = j < 16;
  u16* p = isq ? (qbuf + (size_t)tok * 2048 + j * 128)
               : (kvb + (size_t)tok * 1024 + (j - 16) * 128);
  const float* scale = isq ? qsc : ksc;
  const float mult = isq ? 0.0625f : 1.0f;
  float e0 = b2f(p[lane]), e1 = b2f(p[lane + 64]);
  float ss = e0 * e0 + e1 * e1;
#pragma unroll
  for (int off = 32; off > 0; off >>= 1) ss += __shfl_xor(ss, off);
  float rr = rsqrtf(ss * (1.0f / 128.0f) + 1e-6f);
  float x0 = e0 * rr * scale[lane];
  float x1 = e1 * rr * scale[lane + 64];
  float c0 = cosb[s * 128 + lane], c1 = cosb[s * 128 + 64 + lane];
  float sn0 = sinb[s * 128 + lane], sn1 = sinb[s * 128 + 64 + lane];
  p[lane]      = f2bf((x0 * c0 - x1 * sn0) * mult);
  p[lane + 64] = f2bf((x1 * c1 + x0 * sn1) * mult);
}

// ---------------------------------------------------------------------------
// MFMA flash attention (causal, GQA). 128-row q-tiles, 4 waves x 32 q-rows.
// Each kf/vf LDS read feeds 2 MFMAs (halved LDS-pipe pressure vs 16 q/wave).
// PV computed transposed (A = V^T, B = P^T) so the D-layout has col = q =
// lane&15: softmax state, alpha rescale and 1/ls are lane-local (no
// shuffles), and the ctx write is a vectorized ushort4 store.
// Double-buffered K/V staging via global_load_lds with both-sides XOR
// swizzle; one barrier per tile. P goes through a per-wave chunked LDS
// buffer [32 q][32 key] stride 40 (16B-aligned rows, bank-conflict-free;
// in-order per-wave DS ops make the chunk reuse safe without barriers).
// Grid: 512 blocks 1D, complementary LPT pairing: block i<256 -> qt=15-(i>>5),
// block i+256 -> qt=(i>>5). Round-robin dispatch (mod-8 XCD interleave
// preserved since 256%8==0) pairs them on one CU -> uniform 34 tiles/CU.
// Waves 0/1 skip their fully-masked last tile (wave-uniform branch).
// LDS: 32K Ks + 32K Vs + 10K Ps = 75,776 B -> 2 blocks/CU.
// ---------------------------------------------------------------------------
__global__ __launch_bounds__(256, 2) void attn_mfma(const u16* __restrict__ qb,
                                                    const u16* __restrict__ kv,
                                                    const u16* __restrict__ vT,
                                                    u16* __restrict__ ctx) {
  __shared__ u16 Ks[2][64 * 128];   // [key][d] linear, chunk^=(key&7)
  __shared__ u16 Vs[2][128 * 64];   // [d][key] linear, chunk^=(d&7)
  __shared__ u16 Ps[4][32 * 40];    // per-wave P chunk [q][key] stride 40
  const int i = blockIdx.x;
  const int qt = (i < 256) ? (15 - (i >> 5)) : ((i - 256) >> 5);
  const int hb = i & 31;
  const int h = hb & 15, b = hb >> 4;
  const int t = threadIdx.x, w = t >> 6, lane = t & 63;
  const int lrow = lane & 15, quad = lane >> 4;
  const int kvh = h >> 2;
  const int qw = qt * 128 + w * 32;  // wave's first q row

  const u16* kbase = kv + (size_t)b * Ss * 1024 + kvh * 128;   // key stride 1024
  const u16* vbase = vT + (size_t)(b * KVH + kvh) * 128 * Ss;  // + d*Ss + s

  // staging decomposition: thread t stages LDS chunk (p*256+t) each p.
  // Global source chunk pre-XORed with (row&7) (p-independent: 16p%8==0).
  const int kr  = t >> 4;
  const int kco = ((t & 15) ^ (kr & 7)) * 8;   // u16 offset within K row
  const int vr  = t >> 3;
  const int vco = ((t & 7) ^ (vr & 7)) * 8;    // u16 offset within V row
  const int sw8 = (lrow & 7) << 3;             // read-side XOR (u16 units)

  // stationary Q B-frags: qf[g][c] -> Q[qw+g*16+lrow][c*32+quad*8 ..+7]
  bf16x8 qf[2][4];
#pragma unroll
  for (int g = 0; g < 2; g++)
#pragma unroll
    for (int c = 0; c < 4; c++)
      qf[g][c] = *reinterpret_cast<const bf16x8*>(
          qb + ((size_t)(b * Ss + qw + g * 16 + lrow) * Hh + h) * 128 + c * 32 + quad * 8);

  f32x4 o[2][8];  // o[g][n]: d = n*16+quad*4+r, q = qw+g*16+lrow
#pragma unroll
  for (int g = 0; g < 2; g++)
#pragma unroll
    for (int n = 0; n < 8; n++) o[g][n] = (f32x4)0.f;
  float mx[2] = {-1e30f, -1e30f}, ls[2] = {0.f, 0.f};

  const int ntile = 2 * qt + 2;

  // prologue: stage tile 0 into buffer 0
#pragma unroll
  for (int p = 0; p < 4; p++) {
    gl16(kbase + (size_t)(p * 16 + kr) * 1024 + kco,
         (char*)Ks[0] + (p * 256 + t) * 16);
    gl16(vbase + (size_t)(p * 32 + vr) * Ss + vco,
         (char*)Vs[0] + (p * 256 + t) * 16);
  }
  __syncthreads();

  int cur = 0;
  for (int kt = 0; kt < ntile; kt++) {
    const int kb0 = kt * 64;
    // issue next tile's loads into the other buffer (hidden under compute)
    if (kt + 1 < ntile) {
      const int nb0 = kb0 + 64;
#pragma unroll
      for (int p = 0; p < 4; p++) {
        gl16(kbase + (size_t)(nb0 + p * 16 + kr) * 1024 + kco,
             (char*)Ks[cur ^ 1] + (p * 256 + t) * 16);
        gl16(vbase + (size_t)(p * 32 + vr) * Ss + nb0 + vco,
             (char*)Vs[cur ^ 1] + (p * 256 + t) * 16);
      }
    }

    // waves whose q-rows are all below this key-tile skip compute entirely
    // (wave-uniform; barriers below still run on all waves)
    if (kb0 <= qw + 31) {
      // S^T[key][q]: st[g][mt], key = kb0+mt*16+quad*4+r, q = qw+g*16+lrow
      f32x4 st[2][4];
#pragma unroll
      for (int g = 0; g < 2; g++)
#pragma unroll
        for (int mt = 0; mt < 4; mt++) st[g][mt] = (f32x4)0.f;
#pragma unroll
      for (int c = 0; c < 4; c++) {
        bf16x8 kf[4];
#pragma unroll
        for (int mt = 0; mt < 4; mt++)
          kf[mt] = *reinterpret_cast<const bf16x8*>(
              &Ks[cur][(mt * 16 + lrow) * 128 + ((((c * 4 + quad) << 3)) ^ sw8)]);
        __builtin_amdgcn_s_setprio(1);
#pragma unroll
        for (int mt = 0; mt < 4; mt++)
#pragma unroll
          for (int g = 0; g < 2; g++)
            st[g][mt] =
                __builtin_amdgcn_mfma_f32_16x16x32_bf16(kf[mt], qf[g][c], st[g][mt], 0, 0, 0);
        __builtin_amdgcn_s_setprio(0);
      }
      // causal mask near diagonal
      if (kb0 + 63 > qw) {
#pragma unroll
        for (int g = 0; g < 2; g++) {
          int qg = qw + g * 16 + lrow;
#pragma unroll
          for (int mt = 0; mt < 4; mt++) {
            int kg = kb0 + mt * 16 + quad * 4;
#pragma unroll
            for (int r = 0; r < 4; r++)
              st[g][mt][r] = (kg + r > qg) ? -1e30f : st[g][mt][r];
          }
        }
      }
      // online softmax; state per q = lrow (lane-local, replicated over quads)
      float alpha[2];
#pragma unroll
      for (int g = 0; g < 2; g++) {
        f32x4 m4;
#pragma unroll
        for (int r = 0; r < 4; r++)
          m4[r] = fmaxf(fmaxf(st[g][0][r], st[g][1][r]), fmaxf(st[g][2][r], st[g][3][r]));
        float tm = fmaxf(fmaxf(m4[0], m4[1]), fmaxf(m4[2], m4[3]));
        tm = fmaxf(tm, __shfl_xor(tm, 16));
        tm = fmaxf(tm, __shfl_xor(tm, 32));
        float mn = fmaxf(mx[g], tm);
        alpha[g] = __expf(mx[g] - mn);
        mx[g] = mn;
        float tsum = 0.f;
#pragma unroll
        for (int mt = 0; mt < 4; mt++)
#pragma unroll
          for (int r = 0; r < 4; r++) {
            float pv = __expf(st[g][mt][r] - mn);
            st[g][mt][r] = pv;
            tsum += pv;
          }
        tsum += __shfl_xor(tsum, 16);
        tsum += __shfl_xor(tsum, 32);
        ls[g] = ls[g] * alpha[g] + tsum;
      }
      // rescale O (lane-local alpha: o column q = lrow)
#pragma unroll
      for (int g = 0; g < 2; g++)
#pragma unroll
        for (int n = 0; n < 8; n++) o[g][n] *= alpha[g];
      // PV in 2 key-chunks of 32: pack P chunk -> per-wave LDS -> read as
      // B-frag P^T[k][q]; per-wave in-order DS ops make reuse safe.
#pragma unroll
      for (int c2 = 0; c2 < 2; c2++) {
#pragma unroll
        for (int g = 0; g < 2; g++)
#pragma unroll
          for (int mh = 0; mh < 2; mh++) {
            const f32x4 sv = st[g][c2 * 2 + mh];
            ushort4 pk;
            pk.x = f2bf(sv[0]); pk.y = f2bf(sv[1]);
            pk.z = f2bf(sv[2]); pk.w = f2bf(sv[3]);
            *reinterpret_cast<ushort4*>(
                &Ps[w][(g * 16 + lrow) * 40 + mh * 16 + quad * 4]) = pk;
          }
        bf16x8 pfr[2];
#pragma unroll
        for (int g = 0; g < 2; g++)
          pfr[g] = *reinterpret_cast<const bf16x8*>(
              &Ps[w][(g * 16 + lrow) * 40 + quad * 8]);
        __builtin_amdgcn_s_setprio(1);
#pragma unroll
        for (int n = 0; n < 8; n++) {
          bf16x8 vf = *reinterpret_cast<const bf16x8*>(
              &Vs[cur][(n * 16 + lrow) * 64 + ((((c2 * 4 + quad) << 3)) ^ sw8)]);
#pragma unroll
          for (int g = 0; g < 2; g++)
            o[g][n] = __builtin_amdgcn_mfma_f32_16x16x32_bf16(vf, pfr[g], o[g][n], 0, 0, 0);
        }
        __builtin_amdgcn_s_setprio(0);
      }
    }

    // one barrier per tile: implicit vmcnt(0)+lgkmcnt(0) drains the gl16s
    // issued at the top of this iteration (they had the compute to land).
    __syncthreads();
    cur ^= 1;
  }

  // epilogue: divide by l (lane-local), vectorized bf16 store
#pragma unroll
  for (int g = 0; g < 2; g++) {
    float linv = 1.0f / ls[g];
    u16* obase = ctx + ((size_t)(b * Ss + qw + g * 16 + lrow) * Hh + h) * 128 + quad * 4;
#pragma unroll
    for (int n = 0; n < 8; n++) {
      ushort4 pk;
      pk.x = f2bf(o[g][n][0] * linv);
      pk.y = f2bf(o[g][n][1] * linv);
      pk.z = f2bf(o[g][n][2] * linv);
      pk.w = f2bf(o[g][n][3] * linv);
      *reinterpret_cast<ushort4*>(obase + n * 16) = pk;
    }
  }
}

// ---------------------------------------------------------------------------
extern "C" void kernel_launch(void* const* d_in, const int* in_sizes, int n_in,
                              void* d_out, int out_size, void* d_ws, size_t ws_size,
                              hipStream_t stream) {
  const float* x    = (const float*)d_in[0];
  // d_in[1] = mask (unused; causal handled analytically)
  const float* cosb = (const float*)d_in[2];
  const float* sinb = (const float*)d_in[3];
  const float* Wq   = (const float*)d_in[4];
  const float* Wk   = (const float*)d_in[5];
  const float* Wv   = (const float*)d_in[6];
  const float* Wo   = (const float*)d_in[7];
  const float* qsc  = (const float*)d_in[8];
  const float* ksc  = (const float*)d_in[9];

  const int M = 2 * Ss;  // 4096 tokens
  // workspace (u16 elems); ctxb aliases xb (xb dead after kv gemm)
  u16* xb   = (u16*)d_ws;                      // 8,388,608
  u16* ctxb = xb;                              // alias
  u16* Wt   = xb + (size_t)8388608;            // 4,194,304 (reused per-W)
  u16* qbuf = Wt + (size_t)4194304;            // 8,388,608
  u16* kvb  = qbuf + (size_t)8388608;          // 4,194,304  [tok][1024] k|v
  u16* vTb  = kvb + (size_t)4194304;           // 2,097,152  [(b,kvh)][128][2048]

  cvt_bf16<<<8192, 256, 0, stream>>>(x, xb, 2097152);

  tcvt<<<dim3(32, 32), 256, 0, stream>>>(Wq, Wt, 2048, 2048);
  gemm_bt<0><<<dim3(32, 16), 256, 0, stream>>>(xb, Wt, qbuf, 2048, 2048);

  tcvt<<<dim3(32, 8), 256, 0, stream>>>(Wk, Wt, 512, 2048);                       // rows 0..511
  tcvt<<<dim3(32, 8), 256, 0, stream>>>(Wv, Wt + (size_t)512 * 2048, 512, 2048);  // rows 512..1023
  gemm_bt<0><<<dim3(32, 8), 256, 0, stream>>>(xb, Wt, kvb, 1024, 2048);

  rmsrope2<<<(M * 20) / 4, 256, 0, stream>>>(qbuf, kvb, qsc, ksc, cosb, sinb);

  vtrans<<<dim3(32, 2, 8), 256, 0, stream>>>(kvb, vTb);

  attn_mfma<<<dim3(512), 256, 0, stream>>>(qbuf, kvb, vTb, ctxb);

  tcvt<<<dim3(32, 32), 256, 0, stream>>>(Wo, Wt, 2048, 2048);
  gemm_bt<1><<<dim3(32, 16), 256, 0, stream>>>(ctxb, Wt, d_out, 2048, 2048);
}

// Round 3
// 382.319 us; speedup vs baseline: 1.1411x; 1.0147x over previous
//
#include <hip/hip_runtime.h>
#include <hip/hip_bf16.h>

// GQA fwd: B=2, S=2048, D_IN=2048, H=16, KV=4, Dh=128, GROUP=4, scale=1/16.
// Inputs fp32, output fp32. Intermediates bf16.
// cvt(x)+tcvt(W) -> m97-style bf16 GEMMs (q; fused k|v) -> fused rmsrope(q,k)
// -> vtrans -> MFMA flash attn (64-row q-tiles, 2 waves x 32q, 4 blocks/CU,
// single-buffered XOR-swizzled gl16 staging, defer-max, cvt_pk) -> gemm(out).

using u16 = unsigned short;
using u32 = unsigned int;

constexpr int Ss  = 2048;
constexpr int Hh  = 16;
constexpr int KVH = 4;

typedef __attribute__((ext_vector_type(8))) short bf16x8;
typedef __attribute__((ext_vector_type(4))) float f32x4;

__device__ inline float b2f(u16 v)  { return __uint_as_float(((u32)v) << 16); }
__device__ inline u16 f2bf(float x) {
  u32 u = __float_as_uint(x);
  return (u16)((u + 0x7fffu + ((u >> 16) & 1u)) >> 16);
}
// packed RNE f32x2 -> bf16x2 (no builtin on gfx950; T12 recipe)
__device__ inline u32 cvtpk(float lo, float hi) {
  u32 r;
  asm("v_cvt_pk_bf16_f32 %0, %1, %2" : "=v"(r) : "v"(lo), "v"(hi));
  return r;
}

typedef const __attribute__((address_space(1))) unsigned int gas_u32;
typedef __attribute__((address_space(3))) unsigned int las_u32;
__device__ inline void gl16(const void* g, void* l) {
  __builtin_amdgcn_global_load_lds((gas_u32*)g, (las_u32*)l, 16, 0, 0);
}

// ---------------------------------------------------------------------------
__global__ __launch_bounds__(256) void cvt_bf16(const float* __restrict__ in,
                                                u16* __restrict__ out, int n4) {
  int i = blockIdx.x * 256 + threadIdx.x;
  if (i < n4) {
    float4 f = reinterpret_cast<const float4*>(in)[i];
    ushort4 o;
    o.x = f2bf(f.x); o.y = f2bf(f.y); o.z = f2bf(f.z); o.w = f2bf(f.w);
    reinterpret_cast<ushort4*>(out)[i] = o;
  }
}

// ---------------------------------------------------------------------------
// W [K][N] fp32 -> W^T [N][K] bf16, 64x64 LDS tiles
// ---------------------------------------------------------------------------
__global__ __launch_bounds__(256) void tcvt(const float* __restrict__ in,
                                            u16* __restrict__ out, int N, int K) {
  __shared__ u16 T[64][66];
  const int k0 = blockIdx.x * 64, n0 = blockIdx.y * 64;
  const int c = threadIdx.x & 63, rb = threadIdx.x >> 6;
#pragma unroll
  for (int p = 0; p < 16; p++) {
    int r = p * 4 + rb;
    T[c][r] = f2bf(in[(size_t)(k0 + r) * N + n0 + c]);
  }
  __syncthreads();
#pragma unroll
  for (int p = 0; p < 16; p++) {
    int nr = p * 4 + rb;
    out[(size_t)(n0 + nr) * K + k0 + c] = T[nr][c];
  }
}

// ---------------------------------------------------------------------------
// v half of kv [4096 tok][1024] bf16 -> vT [(b*4+kvh)][128 d][2048 s]
// ---------------------------------------------------------------------------
__global__ __launch_bounds__(256) void vtrans(const u16* __restrict__ kv,
                                              u16* __restrict__ vT) {
  __shared__ u16 T[64][66];
  const int s0 = blockIdx.x * 64, d0 = blockIdx.y * 64, z = blockIdx.z;
  const int b = z >> 2, kvh = z & 3;
  const int c = threadIdx.x & 63, rb = threadIdx.x >> 6;
#pragma unroll
  for (int p = 0; p < 16; p++) {
    int r = p * 4 + rb;
    T[c][r] = kv[(size_t)(b * Ss + s0 + r) * 1024 + 512 + kvh * 128 + d0 + c];
  }
  __syncthreads();
#pragma unroll
  for (int p = 0; p < 16; p++) {
    int dr = p * 4 + rb;
    vT[((size_t)z * 128 + d0 + dr) * Ss + s0 + c] = T[dr][c];
  }
}

// ---------------------------------------------------------------------------
// C[M x N] = A[M x K](bf16) @ Bt[N x K](bf16)^T.  m97 structure.
// ---------------------------------------------------------------------------
template <int OUT_F32>
__global__ __launch_bounds__(256) void gemm_bt(const u16* __restrict__ A,
                                               const u16* __restrict__ Bt,
                                               void* __restrict__ C,
                                               int N, int K) {
  __shared__ u16 As[128 * 64];
  __shared__ u16 Bs[128 * 64];
  const int t = threadIdx.x, w = t >> 6, lane = t & 63;
  const int lrow = lane & 15, quad = lane >> 4;
  const int wm = w & 1, wn = w >> 1;
  const int m0 = blockIdx.x * 128, n0 = blockIdx.y * 128;

  f32x4 acc[4][4];
#pragma unroll
  for (int i = 0; i < 4; i++)
#pragma unroll
    for (int j = 0; j < 4; j++) acc[i][j] = (f32x4)0.f;

  const int srow = t >> 3;
  const int scol = (t & 7) * 8;

  for (int k0 = 0; k0 < K; k0 += 64) {
#pragma unroll
    for (int c = 0; c < 4; c++) {
      gl16(A + (size_t)(m0 + c * 32 + srow) * K + k0 + scol,
           (char*)As + c * 4096 + t * 16);
      gl16(Bt + (size_t)(n0 + c * 32 + srow) * K + k0 + scol,
           (char*)Bs + c * 4096 + t * 16);
    }
    __syncthreads();
#pragma unroll
    for (int kc = 0; kc < 2; kc++) {
      bf16x8 af[4], bfr[4];
#pragma unroll
      for (int i = 0; i < 4; i++) {
        af[i] = *reinterpret_cast<const bf16x8*>(
            &As[(wm * 64 + i * 16 + lrow) * 64 + kc * 32 + quad * 8]);
        bfr[i] = *reinterpret_cast<const bf16x8*>(
            &Bs[(wn * 64 + i * 16 + lrow) * 64 + kc * 32 + quad * 8]);
      }
#pragma unroll
      for (int mi = 0; mi < 4; mi++)
#pragma unroll
        for (int ni = 0; ni < 4; ni++)
          acc[mi][ni] =
              __builtin_amdgcn_mfma_f32_16x16x32_bf16(af[mi], bfr[ni], acc[mi][ni], 0, 0, 0);
    }
    __syncthreads();
  }

#pragma unroll
  for (int mi = 0; mi < 4; mi++)
#pragma unroll
    for (int ni = 0; ni < 4; ni++)
#pragma unroll
      for (int r = 0; r < 4; r++) {
        int row = m0 + wm * 64 + mi * 16 + quad * 4 + r;
        int col = n0 + wn * 64 + ni * 16 + lrow;
        if (OUT_F32)
          reinterpret_cast<float*>(C)[(size_t)row * N + col] = acc[mi][ni][r];
        else
          reinterpret_cast<u16*>(C)[(size_t)row * N + col] = f2bf(acc[mi][ni][r]);
      }
}

// ---------------------------------------------------------------------------
// Fused RMSNorm + RoPE for q and k. 20 vectors/token: j<16 -> q head j
// (stride 2048, mult 1/16), j>=16 -> k head j-16 in kv buffer (stride 1024).
// One wave per vector.
// ---------------------------------------------------------------------------
__global__ __launch_bounds__(256) void rmsrope2(u16* __restrict__ qbuf,
                                                u16* __restrict__ kvb,
                                                const float* __restrict__ qsc,
                                                const float* __restrict__ ksc,
                                                const float* __restrict__ cosb,
                                                const float* __restrict__ sinb) {
  const int w = threadIdx.x >> 6, lane = threadIdx.x & 63;
  const int vi = blockIdx.x * 4 + w;
  const int tok = vi / 20, j = vi - tok * 20;
  const int s = tok & (Ss - 1);
  const bool isq = j < 16;
  u16* p = isq ? (qbuf + (size_t)tok * 2048 + j * 128)
               : (kvb + (size_t)tok * 1024 + (j - 16) * 128);
  const float* scale = isq ? qsc : ksc;
  const float mult = isq ? 0.0625f : 1.0f;
  float e0 = b2f(p[lane]), e1 = b2f(p[lane + 64]);
  float ss = e0 * e0 + e1 * e1;
#pragma unroll
  for (int off = 32; off > 0; off >>= 1) ss += __shfl_xor(ss, off);
  float rr = rsqrtf(ss * (1.0f / 128.0f) + 1e-6f);
  float x0 = e0 * rr * scale[lane];
  float x1 = e1 * rr * scale[lane + 64];
  float c0 = cosb[s * 128 + lane], c1 = cosb[s * 128 + 64 + lane];
  float sn0 = sinb[s * 128 + lane], sn1 = sinb[s * 128 + 64 + lane];
  p[lane]      = f2bf((x0 * c0 - x1 * sn0) * mult);
  p[lane + 64] = f2bf((x1 * c1 + x0 * sn1) * mult);
}

// ---------------------------------------------------------------------------
// MFMA flash attention (causal, GQA). 64-row q-tiles, 2 waves x 32 q-rows.
// 1024 blocks x 128 threads, LDS 37.9KB -> 4 blocks/CU resident = 8 waves/CU
// = 2 waves/SIMD from FOUR different (unsynced) blocks: LDS/MFMA/VALU pipes
// overlap across blocks instead of serializing per-wave.
// Per-CU work made uniform by construction: round-robin dispatch gives CU
// group c blocks {c, c+256, c+512, c+768}; qt map (k=0:31-x, 1:x, 2:23-x,
// 3:8+x) makes every quadruple sum to 66 rounds.
// Single-buffered K/V staging via global_load_lds (both-sides XOR swizzle),
// 2 barriers/tile; cross-block diversity hides the staging stall.
// S^T = K.Q^T; lane-local softmax (state per q = lane&15); defer-max (T13,
// THR=8): skip alpha/O-rescale unless row-max grows >8 (output-exact).
// P pack + epilogue via v_cvt_pk_bf16_f32 (saves ~100 VALU/wave-tile).
// PV transposed (A=V^T, B=P^T) -> vectorized ushort4 ctx store.
// ---------------------------------------------------------------------------
__global__ __launch_bounds__(128, 2) void attn_mfma(const u16* __restrict__ qb,
                                                    const u16* __restrict__ kv,
                                                    const u16* __restrict__ vT,
                                                    u16* __restrict__ ctx) {
  __shared__ u16 Ks[64 * 128];   // [key][d] linear, chunk^=(key&7)
  __shared__ u16 Vs[128 * 64];   // [d][key] linear, chunk^=(d&7)
  __shared__ u16 Ps[2][32 * 40]; // per-wave P chunk [q][key] stride 40
  const int i = blockIdx.x;
  const int kq = i >> 8, jj = i & 255, x = jj >> 5, hb = jj & 31;
  const int qtile = (kq == 0) ? 31 - x : (kq == 1) ? x : (kq == 2) ? 23 - x : 8 + x;
  const int h = hb & 15, b = hb >> 4;
  const int t = threadIdx.x, w = t >> 6, lane = t & 63;
  const int lrow = lane & 15, quad = lane >> 4;
  const int kvh = h >> 2;
  const int qw = qtile * 64 + w * 32;  // wave's first q row

  const u16* kbase = kv + (size_t)b * Ss * 1024 + kvh * 128;   // key stride 1024
  const u16* vbase = vT + (size_t)(b * KVH + kvh) * 128 * Ss;  // + d*Ss + s

  // staging: thread t stages chunk (p8*128+t) each p8 (8 K + 8 V gl16).
  // Global source chunk pre-XORed with (row&7) (p8-independent).
  const int kr  = t >> 4;                       // K row 0..7 (+p8*8)
  const int kco = ((t & 15) ^ (kr & 7)) * 8;    // u16 offset within K row
  const int vr  = t >> 3;                       // V row 0..15 (+p8*16)
  const int vco = ((t & 7) ^ (vr & 7)) * 8;     // u16 offset within V row
  const int sw8 = (lrow & 7) << 3;              // read-side XOR (u16 units)

  // stationary Q B-frags: qf[g][c] -> Q[qw+g*16+lrow][c*32+quad*8 ..+7]
  bf16x8 qf[2][4];
#pragma unroll
  for (int g = 0; g < 2; g++)
#pragma unroll
    for (int c = 0; c < 4; c++)
      qf[g][c] = *reinterpret_cast<const bf16x8*>(
          qb + ((size_t)(b * Ss + qw + g * 16 + lrow) * Hh + h) * 128 + c * 32 + quad * 8);

  f32x4 o[2][8];  // o[g][n]: d = n*16+quad*4+r, q = qw+g*16+lrow
#pragma unroll
  for (int g = 0; g < 2; g++)
#pragma unroll
    for (int n = 0; n < 8; n++) o[g][n] = (f32x4)0.f;
  float mx[2] = {-1e30f, -1e30f}, ls[2] = {0.f, 0.f};

  const int ntile = qtile + 1;
  for (int kt = 0; kt < ntile; kt++) {
    const int kb0 = kt * 64;
    __syncthreads();  // all waves done reading previous tile's LDS
#pragma unroll
    for (int p8 = 0; p8 < 8; p8++) {
      gl16(kbase + (size_t)(kb0 + p8 * 8 + kr) * 1024 + kco,
           (char*)Ks + (p8 * 128 + t) * 16);
      gl16(vbase + (size_t)(p8 * 16 + vr) * Ss + kb0 + vco,
           (char*)Vs + (p8 * 128 + t) * 16);
    }
    __syncthreads();  // implicit vmcnt(0): staged tile ready

    // S^T[key][q]: st[g][mt], key = kb0+mt*16+quad*4+r, q = qw+g*16+lrow
    f32x4 st[2][4];
#pragma unroll
    for (int g = 0; g < 2; g++)
#pragma unroll
      for (int mt = 0; mt < 4; mt++) st[g][mt] = (f32x4)0.f;
#pragma unroll
    for (int c = 0; c < 4; c++) {
      bf16x8 kf[4];
#pragma unroll
      for (int mt = 0; mt < 4; mt++)
        kf[mt] = *reinterpret_cast<const bf16x8*>(
            &Ks[(mt * 16 + lrow) * 128 + ((((c * 4 + quad) << 3)) ^ sw8)]);
      __builtin_amdgcn_s_setprio(1);
#pragma unroll
      for (int mt = 0; mt < 4; mt++)
#pragma unroll
        for (int g = 0; g < 2; g++)
          st[g][mt] =
              __builtin_amdgcn_mfma_f32_16x16x32_bf16(kf[mt], qf[g][c], st[g][mt], 0, 0, 0);
      __builtin_amdgcn_s_setprio(0);
    }
    // causal mask (only the diagonal tile)
    if (kb0 + 63 > qw) {
#pragma unroll
      for (int g = 0; g < 2; g++) {
        int qg = qw + g * 16 + lrow;
#pragma unroll
        for (int mt = 0; mt < 4; mt++) {
          int kg = kb0 + mt * 16 + quad * 4;
#pragma unroll
          for (int r = 0; r < 4; r++)
            st[g][mt][r] = (kg + r > qg) ? -1e30f : st[g][mt][r];
        }
      }
    }
    // online softmax, lane-local state (q = lrow, replicated over quads)
    float tmv[2];
#pragma unroll
    for (int g = 0; g < 2; g++) {
      f32x4 m4;
#pragma unroll
      for (int r = 0; r < 4; r++)
        m4[r] = fmaxf(fmaxf(st[g][0][r], st[g][1][r]), fmaxf(st[g][2][r], st[g][3][r]));
      float tm = fmaxf(fmaxf(m4[0], m4[1]), fmaxf(m4[2], m4[3]));
      tm = fmaxf(tm, __shfl_xor(tm, 16));
      tm = fmaxf(tm, __shfl_xor(tm, 32));
      tmv[g] = tm;
    }
    // defer-max (T13): rescale only if some row grew its max by >8.
    // P = exp(s - mx) stays <= e^8; o/ls ratio is mx-independent (exact).
    if (__any((tmv[0] > mx[0] + 8.0f) || (tmv[1] > mx[1] + 8.0f))) {
#pragma unroll
      for (int g = 0; g < 2; g++) {
        float mn = fmaxf(mx[g], tmv[g]);
        float a = __expf(mx[g] - mn);
        mx[g] = mn;
        ls[g] *= a;
#pragma unroll
        for (int n = 0; n < 8; n++) o[g][n] *= a;
      }
    }
#pragma unroll
    for (int g = 0; g < 2; g++) {
      float tsum = 0.f;
#pragma unroll
      for (int mt = 0; mt < 4; mt++)
#pragma unroll
        for (int r = 0; r < 4; r++) {
          float pv = __expf(st[g][mt][r] - mx[g]);
          st[g][mt][r] = pv;
          tsum += pv;
        }
      tsum += __shfl_xor(tsum, 16);
      tsum += __shfl_xor(tsum, 32);
      ls[g] += tsum;
    }
    // PV in 2 key-chunks of 32: pack P (cvt_pk) -> per-wave LDS -> B-frag
    // P^T[k][q]; per-wave in-order DS ops make the chunk reuse safe.
#pragma unroll
    for (int c2 = 0; c2 < 2; c2++) {
#pragma unroll
      for (int g = 0; g < 2; g++)
#pragma unroll
        for (int mh = 0; mh < 2; mh++) {
          const f32x4 sv = st[g][c2 * 2 + mh];
          uint2 pk;
          pk.x = cvtpk(sv[0], sv[1]);
          pk.y = cvtpk(sv[2], sv[3]);
          *reinterpret_cast<uint2*>(
              &Ps[w][(g * 16 + lrow) * 40 + mh * 16 + quad * 4]) = pk;
        }
      bf16x8 pfr[2];
#pragma unroll
      for (int g = 0; g < 2; g++)
        pfr[g] = *reinterpret_cast<const bf16x8*>(
            &Ps[w][(g * 16 + lrow) * 40 + quad * 8]);
      __builtin_amdgcn_s_setprio(1);
#pragma unroll
      for (int n = 0; n < 8; n++) {
        bf16x8 vf = *reinterpret_cast<const bf16x8*>(
            &Vs[(n * 16 + lrow) * 64 + ((((c2 * 4 + quad) << 3)) ^ sw8)]);
#pragma unroll
        for (int g = 0; g < 2; g++)
          o[g][n] = __builtin_amdgcn_mfma_f32_16x16x32_bf16(vf, pfr[g], o[g][n], 0, 0, 0);
      }
      __builtin_amdgcn_s_setprio(0);
    }
  }

  // epilogue: divide by l (lane-local), packed bf16 store
#pragma unroll
  for (int g = 0; g < 2; g++) {
    float linv = 1.0f / ls[g];
    u16* obase = ctx + ((size_t)(b * Ss + qw + g * 16 + lrow) * Hh + h) * 128 + quad * 4;
#pragma unroll
    for (int n = 0; n < 8; n++) {
      uint2 pk;
      pk.x = cvtpk(o[g][n][0] * linv, o[g][n][1] * linv);
      pk.y = cvtpk(o[g][n][2] * linv, o[g][n][3] * linv);
      *reinterpret_cast<uint2*>(obase + n * 16) = pk;
    }
  }
}

// ---------------------------------------------------------------------------
extern "C" void kernel_launch(void* const* d_in, const int* in_sizes, int n_in,
                              void* d_out, int out_size, void* d_ws, size_t ws_size,
                              hipStream_t stream) {
  const float* x    = (const float*)d_in[0];
  // d_in[1] = mask (unused; causal handled analytically)
  const float* cosb = (const float*)d_in[2];
  const float* sinb = (const float*)d_in[3];
  const float* Wq   = (const float*)d_in[4];
  const float* Wk   = (const float*)d_in[5];
  const float* Wv   = (const float*)d_in[6];
  const float* Wo   = (const float*)d_in[7];
  const float* qsc  = (const float*)d_in[8];
  const float* ksc  = (const float*)d_in[9];

  const int M = 2 * Ss;  // 4096 tokens
  // workspace (u16 elems); ctxb aliases xb (xb dead after kv gemm)
  u16* xb   = (u16*)d_ws;                      // 8,388,608
  u16* ctxb = xb;                              // alias
  u16* Wt   = xb + (size_t)8388608;            // 4,194,304 (reused per-W)
  u16* qbuf = Wt + (size_t)4194304;            // 8,388,608
  u16* kvb  = qbuf + (size_t)8388608;          // 4,194,304  [tok][1024] k|v
  u16* vTb  = kvb + (size_t)4194304;           // 2,097,152  [(b,kvh)][128][2048]

  cvt_bf16<<<8192, 256, 0, stream>>>(x, xb, 2097152);

  tcvt<<<dim3(32, 32), 256, 0, stream>>>(Wq, Wt, 2048, 2048);
  gemm_bt<0><<<dim3(32, 16), 256, 0, stream>>>(xb, Wt, qbuf, 2048, 2048);

  tcvt<<<dim3(32, 8), 256, 0, stream>>>(Wk, Wt, 512, 2048);                       // rows 0..511
  tcvt<<<dim3(32, 8), 256, 0, stream>>>(Wv, Wt + (size_t)512 * 2048, 512, 2048);  // rows 512..1023
  gemm_bt<0><<<dim3(32, 8), 256, 0, stream>>>(xb, Wt, kvb, 1024, 2048);

  rmsrope2<<<(M * 20) / 4, 256, 0, stream>>>(qbuf, kvb, qsc, ksc, cosb, sinb);

  vtrans<<<dim3(32, 2, 8), 256, 0, stream>>>(kvb, vTb);

  attn_mfma<<<dim3(1024), 128, 0, stream>>>(qbuf, kvb, vTb, ctxb);

  tcvt<<<dim3(32, 32), 256, 0, stream>>>(Wo, Wt, 2048, 2048);
  gemm_bt<1><<<dim3(32, 16), 256, 0, stream>>>(ctxb, Wt, d_out, 2048, 2048);
}

// Round 4
// 362.391 us; speedup vs baseline: 1.2039x; 1.0550x over previous
//
#include <hip/hip_runtime.h>
#include <hip/hip_bf16.h>

// GQA fwd: B=2, S=2048, D_IN=2048, H=16, KV=4, Dh=128, GROUP=4, scale=1/16.
// Inputs fp32, output fp32. Intermediates bf16.
// cvt(x)+tcvt(W) -> fused QKV 256^2-tile counted-vmcnt GEMM -> rmsrope(q,k)
// -> vtrans -> MFMA flash attn (R3 structure, ctx in-place into qbuf)
// -> 256^2 out GEMM (f32).
// Workspace identical 54.5MB footprint: vTb aliases dead xb; ctx in-place in
// qbuf; Wo^T aliases dead Wqkv.

using u16 = unsigned short;
using u32 = unsigned int;

constexpr int Ss  = 2048;
constexpr int Hh  = 16;
constexpr int KVH = 4;

typedef __attribute__((ext_vector_type(8))) short bf16x8;
typedef __attribute__((ext_vector_type(4))) float f32x4;

__device__ inline float b2f(u16 v)  { return __uint_as_float(((u32)v) << 16); }
__device__ inline u16 f2bf(float x) {
  u32 u = __float_as_uint(x);
  return (u16)((u + 0x7fffu + ((u >> 16) & 1u)) >> 16);
}
// packed RNE f32x2 -> bf16x2
__device__ inline u32 cvtpk(float lo, float hi) {
  u32 r;
  asm("v_cvt_pk_bf16_f32 %0, %1, %2" : "=v"(r) : "v"(lo), "v"(hi));
  return r;
}

typedef const __attribute__((address_space(1))) unsigned int gas_u32;
typedef __attribute__((address_space(3))) unsigned int las_u32;
__device__ inline void gl16(const void* g, void* l) {
  __builtin_amdgcn_global_load_lds((gas_u32*)g, (las_u32*)l, 16, 0, 0);
}

// ---------------------------------------------------------------------------
__global__ __launch_bounds__(256) void cvt_bf16(const float* __restrict__ in,
                                                u16* __restrict__ out, int n4) {
  int i = blockIdx.x * 256 + threadIdx.x;
  if (i < n4) {
    float4 f = reinterpret_cast<const float4*>(in)[i];
    ushort4 o;
    o.x = f2bf(f.x); o.y = f2bf(f.y); o.z = f2bf(f.z); o.w = f2bf(f.w);
    reinterpret_cast<ushort4*>(out)[i] = o;
  }
}

// ---------------------------------------------------------------------------
// W [K][N] fp32 -> W^T [N][K] bf16, 64x64 LDS tiles
// ---------------------------------------------------------------------------
__global__ __launch_bounds__(256) void tcvt(const float* __restrict__ in,
                                            u16* __restrict__ out, int N, int K) {
  __shared__ u16 T[64][66];
  const int k0 = blockIdx.x * 64, n0 = blockIdx.y * 64;
  const int c = threadIdx.x & 63, rb = threadIdx.x >> 6;
#pragma unroll
  for (int p = 0; p < 16; p++) {
    int r = p * 4 + rb;
    T[c][r] = f2bf(in[(size_t)(k0 + r) * N + n0 + c]);
  }
  __syncthreads();
#pragma unroll
  for (int p = 0; p < 16; p++) {
    int nr = p * 4 + rb;
    out[(size_t)(n0 + nr) * K + k0 + c] = T[nr][c];
  }
}

// ---------------------------------------------------------------------------
// v half of kv [4096 tok][1024] bf16 -> vT [(b*4+kvh)][128 d][2048 s]
// ---------------------------------------------------------------------------
__global__ __launch_bounds__(256) void vtrans(const u16* __restrict__ kv,
                                              u16* __restrict__ vT) {
  __shared__ u16 T[64][66];
  const int s0 = blockIdx.x * 64, d0 = blockIdx.y * 64, z = blockIdx.z;
  const int b = z >> 2, kvh = z & 3;
  const int c = threadIdx.x & 63, rb = threadIdx.x >> 6;
#pragma unroll
  for (int p = 0; p < 16; p++) {
    int r = p * 4 + rb;
    T[c][r] = kv[(size_t)(b * Ss + s0 + r) * 1024 + 512 + kvh * 128 + d0 + c];
  }
  __syncthreads();
#pragma unroll
  for (int p = 0; p < 16; p++) {
    int dr = p * 4 + rb;
    vT[((size_t)z * 128 + d0 + dr) * Ss + s0 + c] = T[dr][c];
  }
}

// ---------------------------------------------------------------------------
// 256x256-tile GEMM, BK=64, 512 threads (8 waves 4Mx2N, per-wave 64x128).
// C[M x N] = A[M x K](bf16) @ Bt[N x K](bf16)^T.
// Double-buffered LDS (128KB, 1 block/CU, 2 waves/SIMD), counted-vmcnt
// pipeline: STAGE kt+2 after the read-done barrier, then s_waitcnt vmcnt(8)
// (= one STAGE's 8 gl16s still in flight) + raw s_barrier -- loads span
// barriers, never drained to 0 in steady state (T3/T4).
// Per K-tile per wave: 64 MFMA vs 24 ds_read_b128 -> MFMA-bound regime.
// Both-sides XOR chunk swizzle (row&7) on A/B tiles (T2, proven pattern).
// MODE 0: split bf16 output: cols<2048 -> C0 stride 2048 (q), cols>=2048 ->
//         C1 stride 1024 (kv). MODE 1: f32 output C0 stride 2048.
// ---------------------------------------------------------------------------
template <int MODE>
__global__ __launch_bounds__(512, 2) void gemm256(const u16* __restrict__ A,
                                                  const u16* __restrict__ Bt,
                                                  void* __restrict__ C0,
                                                  u16* __restrict__ C1,
                                                  int K) {
  __shared__ u16 As[2][256 * 64];
  __shared__ u16 Bs[2][256 * 64];
  const int t = threadIdx.x;
  const int wid = t >> 6, lane = t & 63;
  const int lrow = lane & 15, quad = lane >> 4;
  const int wm = wid >> 1, wn = wid & 1;  // 4x2 wave grid; per-wave 64 x 128
  const int m0 = blockIdx.x * 256, n0 = blockIdx.y * 256;
  const int sw8 = (lrow & 7) << 3;

  // staging: thread t stages chunks p*512+t (p=0..3) per operand per K-tile.
  // LDS chunk c holds global col-chunk (c&7)^(row&7) of row c>>3 (both-sides
  // XOR swizzle; read applies the same XOR).
  const int srow = t >> 3;                  // 0..63 within a 64-row group
  const int sco  = ((t & 7) ^ (srow & 7)) * 8;  // swizzled src col (u16)

  f32x4 acc[4][8];
#pragma unroll
  for (int i = 0; i < 4; i++)
#pragma unroll
    for (int j = 0; j < 8; j++) acc[i][j] = (f32x4)0.f;

#define STAGE(buf, k0)                                                     \
  {                                                                        \
    _Pragma("unroll") for (int p = 0; p < 4; p++) {                        \
      gl16(A + (size_t)(m0 + p * 64 + srow) * K + (k0) + sco,              \
           (char*)As[buf] + (p * 512 + t) * 16);                           \
      gl16(Bt + (size_t)(n0 + p * 64 + srow) * K + (k0) + sco,             \
           (char*)Bs[buf] + (p * 512 + t) * 16);                           \
    }                                                                      \
  }

  const int nk = K >> 6;  // 32
  STAGE(0, 0)
  STAGE(1, 64)
  asm volatile("s_waitcnt vmcnt(8)" ::: "memory");  // buf0 complete
  __builtin_amdgcn_s_barrier();
  __builtin_amdgcn_sched_barrier(0);

  for (int kt = 0; kt < nk; ++kt) {
    const int buf = kt & 1;
#pragma unroll
    for (int kc = 0; kc < 2; kc++) {
      bf16x8 af[4], bfr[8];
#pragma unroll
      for (int i = 0; i < 4; i++)
        af[i] = *reinterpret_cast<const bf16x8*>(
            &As[buf][(wm * 64 + i * 16 + lrow) * 64 + (((kc * 4 + quad) << 3) ^ sw8)]);
#pragma unroll
      for (int j = 0; j < 8; j++)
        bfr[j] = *reinterpret_cast<const bf16x8*>(
            &Bs[buf][(wn * 128 + j * 16 + lrow) * 64 + (((kc * 4 + quad) << 3) ^ sw8)]);
      __builtin_amdgcn_s_setprio(1);
#pragma unroll
      for (int i = 0; i < 4; i++)
#pragma unroll
        for (int j = 0; j < 8; j++)
          acc[i][j] =
              __builtin_amdgcn_mfma_f32_16x16x32_bf16(af[i], bfr[j], acc[i][j], 0, 0, 0);
      __builtin_amdgcn_s_setprio(0);
    }
    __builtin_amdgcn_sched_barrier(0);
    __builtin_amdgcn_s_barrier();  // all waves done reading buf
    __builtin_amdgcn_sched_barrier(0);
    if (kt + 2 < nk) {
      STAGE(buf, (kt + 2) * 64)
    }
    if (kt + 1 < nk) {
      if (kt + 2 < nk) {
        asm volatile("s_waitcnt vmcnt(8)" ::: "memory");  // buf kt+1 ready
      } else {
        asm volatile("s_waitcnt vmcnt(0)" ::: "memory");
      }
      __builtin_amdgcn_s_barrier();
      __builtin_amdgcn_sched_barrier(0);
    }
  }
#undef STAGE

  // epilogue
  if (MODE == 0) {
    u16* C;
    int stride, coff;
    if (n0 < 2048) { C = (u16*)C0; stride = 2048; coff = n0; }
    else           { C = C1;       stride = 1024; coff = n0 - 2048; }
#pragma unroll
    for (int i = 0; i < 4; i++)
#pragma unroll
      for (int j = 0; j < 8; j++)
#pragma unroll
        for (int r = 0; r < 4; r++) {
          int row = m0 + wm * 64 + i * 16 + quad * 4 + r;
          int col = coff + wn * 128 + j * 16 + lrow;
          C[(size_t)row * stride + col] = f2bf(acc[i][j][r]);
        }
  } else {
    float* C = (float*)C0;
#pragma unroll
    for (int i = 0; i < 4; i++)
#pragma unroll
      for (int j = 0; j < 8; j++)
#pragma unroll
        for (int r = 0; r < 4; r++) {
          int row = m0 + wm * 64 + i * 16 + quad * 4 + r;
          int col = n0 + wn * 128 + j * 16 + lrow;
          C[(size_t)row * 2048 + col] = acc[i][j][r];
        }
  }
}

// ---------------------------------------------------------------------------
// Fused RMSNorm + RoPE for q and k. 20 vectors/token: j<16 -> q head j
// (stride 2048, mult 1/16), j>=16 -> k head j-16 in kv buffer (stride 1024).
// One wave per vector.
// ---------------------------------------------------------------------------
__global__ __launch_bounds__(256) void rmsrope2(u16* __restrict__ qbuf,
                                                u16* __restrict__ kvb,
                                                const float* __restrict__ qsc,
                                                const float* __restrict__ ksc,
                                                const float* __restrict__ cosb,
                                                const float* __restrict__ sinb) {
  const int w = threadIdx.x >> 6, lane = threadIdx.x & 63;
  const int vi = blockIdx.x * 4 + w;
  const int tok = vi / 20, j = vi - tok * 20;
  const int s = tok & (Ss - 1);
  const bool isq = j < 16;
  u16* p = isq ? (qbuf + (size_t)tok * 2048 + j * 128)
               : (kvb + (size_t)tok * 1024 + (j - 16) * 128);
  const float* scale = isq ? qsc : ksc;
  const float mult = isq ? 0.0625f : 1.0f;
  float e0 = b2f(p[lane]), e1 = b2f(p[lane + 64]);
  float ss = e0 * e0 + e1 * e1;
#pragma unroll
  for (int off = 32; off > 0; off >>= 1) ss += __shfl_xor(ss, off);
  float rr = rsqrtf(ss * (1.0f / 128.0f) + 1e-6f);
  float x0 = e0 * rr * scale[lane];
  float x1 = e1 * rr * scale[lane + 64];
  float c0 = cosb[s * 128 + lane], c1 = cosb[s * 128 + 64 + lane];
  float sn0 = sinb[s * 128 + lane], sn1 = sinb[s * 128 + 64 + lane];
  p[lane]      = f2bf((x0 * c0 - x1 * sn0) * mult);
  p[lane + 64] = f2bf((x1 * c1 + x0 * sn1) * mult);
}

// ---------------------------------------------------------------------------
// MFMA flash attention (causal, GQA). R3 structure: 64-row q-tiles, 2 waves x
// 32 q-rows, 1024 blocks x 128 threads (4 blocks/CU), single-buffered XOR-
// swizzled gl16 staging, lane-local softmax, defer-max (T13), cvt_pk pack,
// transposed PV. ctx is written IN-PLACE into qbuf (each block reads its
// q-frags in the prologue, writes ctx to the same [tok][h] slots at the end;
// block-exclusive ownership of (token-range, head) makes this race-free).
// ---------------------------------------------------------------------------
__global__ __launch_bounds__(128, 2) void attn_mfma(const u16* __restrict__ qb,
                                                    const u16* __restrict__ kv,
                                                    const u16* __restrict__ vT,
                                                    u16* __restrict__ ctx) {
  __shared__ u16 Ks[64 * 128];   // [key][d] linear, chunk^=(key&7)
  __shared__ u16 Vs[128 * 64];   // [d][key] linear, chunk^=(d&7)
  __shared__ u16 Ps[2][32 * 40]; // per-wave P chunk [q][key] stride 40
  const int i = blockIdx.x;
  const int kq = i >> 8, jj = i & 255, x = jj >> 5, hb = jj & 31;
  const int qtile = (kq == 0) ? 31 - x : (kq == 1) ? x : (kq == 2) ? 23 - x : 8 + x;
  const int h = hb & 15, b = hb >> 4;
  const int t = threadIdx.x, w = t >> 6, lane = t & 63;
  const int lrow = lane & 15, quad = lane >> 4;
  const int kvh = h >> 2;
  const int qw = qtile * 64 + w * 32;  // wave's first q row

  const u16* kbase = kv + (size_t)b * Ss * 1024 + kvh * 128;   // key stride 1024
  const u16* vbase = vT + (size_t)(b * KVH + kvh) * 128 * Ss;  // + d*Ss + s

  const int kr  = t >> 4;                       // K row 0..7 (+p8*8)
  const int kco = ((t & 15) ^ (kr & 7)) * 8;    // u16 offset within K row
  const int vr  = t >> 3;                       // V row 0..15 (+p8*16)
  const int vco = ((t & 7) ^ (vr & 7)) * 8;     // u16 offset within V row
  const int sw8 = (lrow & 7) << 3;              // read-side XOR (u16 units)

  // stationary Q B-frags: qf[g][c] -> Q[qw+g*16+lrow][c*32+quad*8 ..+7]
  bf16x8 qf[2][4];
#pragma unroll
  for (int g = 0; g < 2; g++)
#pragma unroll
    for (int c = 0; c < 4; c++)
      qf[g][c] = *reinterpret_cast<const bf16x8*>(
          qb + ((size_t)(b * Ss + qw + g * 16 + lrow) * Hh + h) * 128 + c * 32 + quad * 8);

  f32x4 o[2][8];  // o[g][n]: d = n*16+quad*4+r, q = qw+g*16+lrow
#pragma unroll
  for (int g = 0; g < 2; g++)
#pragma unroll
    for (int n = 0; n < 8; n++) o[g][n] = (f32x4)0.f;
  float mx[2] = {-1e30f, -1e30f}, ls[2] = {0.f, 0.f};

  const int ntile = qtile + 1;
  for (int kt = 0; kt < ntile; kt++) {
    const int kb0 = kt * 64;
    __syncthreads();  // all waves done reading previous tile's LDS
#pragma unroll
    for (int p8 = 0; p8 < 8; p8++) {
      gl16(kbase + (size_t)(kb0 + p8 * 8 + kr) * 1024 + kco,
           (char*)Ks + (p8 * 128 + t) * 16);
      gl16(vbase + (size_t)(p8 * 16 + vr) * Ss + kb0 + vco,
           (char*)Vs + (p8 * 128 + t) * 16);
    }
    __syncthreads();  // implicit vmcnt(0): staged tile ready

    // S^T[key][q]: st[g][mt], key = kb0+mt*16+quad*4+r, q = qw+g*16+lrow
    f32x4 st[2][4];
#pragma unroll
    for (int g = 0; g < 2; g++)
#pragma unroll
      for (int mt = 0; mt < 4; mt++) st[g][mt] = (f32x4)0.f;
#pragma unroll
    for (int c = 0; c < 4; c++) {
      bf16x8 kf[4];
#pragma unroll
      for (int mt = 0; mt < 4; mt++)
        kf[mt] = *reinterpret_cast<const bf16x8*>(
            &Ks[(mt * 16 + lrow) * 128 + ((((c * 4 + quad) << 3)) ^ sw8)]);
      __builtin_amdgcn_s_setprio(1);
#pragma unroll
      for (int mt = 0; mt < 4; mt++)
#pragma unroll
        for (int g = 0; g < 2; g++)
          st[g][mt] =
              __builtin_amdgcn_mfma_f32_16x16x32_bf16(kf[mt], qf[g][c], st[g][mt], 0, 0, 0);
      __builtin_amdgcn_s_setprio(0);
    }
    // causal mask (only the diagonal tile)
    if (kb0 + 63 > qw) {
#pragma unroll
      for (int g = 0; g < 2; g++) {
        int qg = qw + g * 16 + lrow;
#pragma unroll
        for (int mt = 0; mt < 4; mt++) {
          int kg = kb0 + mt * 16 + quad * 4;
#pragma unroll
          for (int r = 0; r < 4; r++)
            st[g][mt][r] = (kg + r > qg) ? -1e30f : st[g][mt][r];
        }
      }
    }
    // online softmax, lane-local state (q = lrow, replicated over quads)
    float tmv[2];
#pragma unroll
    for (int g = 0; g < 2; g++) {
      f32x4 m4;
#pragma unroll
      for (int r = 0; r < 4; r++)
        m4[r] = fmaxf(fmaxf(st[g][0][r], st[g][1][r]), fmaxf(st[g][2][r], st[g][3][r]));
      float tm = fmaxf(fmaxf(m4[0], m4[1]), fmaxf(m4[2], m4[3]));
      tm = fmaxf(tm, __shfl_xor(tm, 16));
      tm = fmaxf(tm, __shfl_xor(tm, 32));
      tmv[g] = tm;
    }
    // defer-max (T13): rescale only if some row grew its max by >8.
    if (__any((tmv[0] > mx[0] + 8.0f) || (tmv[1] > mx[1] + 8.0f))) {
#pragma unroll
      for (int g = 0; g < 2; g++) {
        float mn = fmaxf(mx[g], tmv[g]);
        float a = __expf(mx[g] - mn);
        mx[g] = mn;
        ls[g] *= a;
#pragma unroll
        for (int n = 0; n < 8; n++) o[g][n] *= a;
      }
    }
#pragma unroll
    for (int g = 0; g < 2; g++) {
      float tsum = 0.f;
#pragma unroll
      for (int mt = 0; mt < 4; mt++)
#pragma unroll
        for (int r = 0; r < 4; r++) {
          float pv = __expf(st[g][mt][r] - mx[g]);
          st[g][mt][r] = pv;
          tsum += pv;
        }
      tsum += __shfl_xor(tsum, 16);
      tsum += __shfl_xor(tsum, 32);
      ls[g] += tsum;
    }
    // PV in 2 key-chunks of 32: pack P (cvt_pk) -> per-wave LDS -> B-frag
#pragma unroll
    for (int c2 = 0; c2 < 2; c2++) {
#pragma unroll
      for (int g = 0; g < 2; g++)
#pragma unroll
        for (int mh = 0; mh < 2; mh++) {
          const f32x4 sv = st[g][c2 * 2 + mh];
          uint2 pk;
          pk.x = cvtpk(sv[0], sv[1]);
          pk.y = cvtpk(sv[2], sv[3]);
          *reinterpret_cast<uint2*>(
              &Ps[w][(g * 16 + lrow) * 40 + mh * 16 + quad * 4]) = pk;
        }
      bf16x8 pfr[2];
#pragma unroll
      for (int g = 0; g < 2; g++)
        pfr[g] = *reinterpret_cast<const bf16x8*>(
            &Ps[w][(g * 16 + lrow) * 40 + quad * 8]);
      __builtin_amdgcn_s_setprio(1);
#pragma unroll
      for (int n = 0; n < 8; n++) {
        bf16x8 vf = *reinterpret_cast<const bf16x8*>(
            &Vs[(n * 16 + lrow) * 64 + ((((c2 * 4 + quad) << 3)) ^ sw8)]);
#pragma unroll
        for (int g = 0; g < 2; g++)
          o[g][n] = __builtin_amdgcn_mfma_f32_16x16x32_bf16(vf, pfr[g], o[g][n], 0, 0, 0);
      }
      __builtin_amdgcn_s_setprio(0);
    }
  }

  // epilogue: divide by l (lane-local), packed bf16 store
#pragma unroll
  for (int g = 0; g < 2; g++) {
    float linv = 1.0f / ls[g];
    u16* obase = ctx + ((size_t)(b * Ss + qw + g * 16 + lrow) * Hh + h) * 128 + quad * 4;
#pragma unroll
    for (int n = 0; n < 8; n++) {
      uint2 pk;
      pk.x = cvtpk(o[g][n][0] * linv, o[g][n][1] * linv);
      pk.y = cvtpk(o[g][n][2] * linv, o[g][n][3] * linv);
      *reinterpret_cast<uint2*>(obase + n * 16) = pk;
    }
  }
}

// ---------------------------------------------------------------------------
extern "C" void kernel_launch(void* const* d_in, const int* in_sizes, int n_in,
                              void* d_out, int out_size, void* d_ws, size_t ws_size,
                              hipStream_t stream) {
  const float* x    = (const float*)d_in[0];
  // d_in[1] = mask (unused; causal handled analytically)
  const float* cosb = (const float*)d_in[2];
  const float* sinb = (const float*)d_in[3];
  const float* Wq   = (const float*)d_in[4];
  const float* Wk   = (const float*)d_in[5];
  const float* Wv   = (const float*)d_in[6];
  const float* Wo   = (const float*)d_in[7];
  const float* qsc  = (const float*)d_in[8];
  const float* ksc  = (const float*)d_in[9];

  const int M = 2 * Ss;  // 4096 tokens
  // workspace (u16 elems), 27,262,976 total (same footprint as before):
  // xb    [0        .. 8388608)   x bf16 [4096][2048]; dead after QKV gemm
  // Wqkv  [8388608  .. 14680064)  W^T [3072][2048]; dead after QKV gemm
  // qbuf  [14680064 .. 23068672)  q [tok][16][128]; ctx written in-place
  // kvb   [23068672 .. 27262976)  k|v [tok][1024]
  // vTb   = alias of xb[0..2097152)   (used from vtrans onward)
  // WoT   = alias of Wqkv[0..4194304) (used from tcvt(Wo) onward)
  u16* xb   = (u16*)d_ws;
  u16* Wqkv = xb + (size_t)8388608;
  u16* qbuf = Wqkv + (size_t)6291456;
  u16* kvb  = qbuf + (size_t)8388608;
  u16* vTb  = xb;
  u16* WoT  = Wqkv;

  cvt_bf16<<<8192, 256, 0, stream>>>(x, xb, 2097152);

  tcvt<<<dim3(32, 32), 256, 0, stream>>>(Wq, Wqkv, 2048, 2048);
  tcvt<<<dim3(32, 8), 256, 0, stream>>>(Wk, Wqkv + (size_t)2048 * 2048, 512, 2048);
  tcvt<<<dim3(32, 8), 256, 0, stream>>>(Wv, Wqkv + (size_t)2560 * 2048, 512, 2048);

  // fused QKV projection: [4096][3072] split into qbuf (cols<2048) / kvb
  gemm256<0><<<dim3(16, 12), 512, 0, stream>>>(xb, Wqkv, qbuf, kvb, 2048);

  rmsrope2<<<(M * 20) / 4, 256, 0, stream>>>(qbuf, kvb, qsc, ksc, cosb, sinb);

  vtrans<<<dim3(32, 2, 8), 256, 0, stream>>>(kvb, vTb);

  attn_mfma<<<dim3(1024), 128, 0, stream>>>(qbuf, kvb, vTb, qbuf /*in-place*/);

  tcvt<<<dim3(32, 32), 256, 0, stream>>>(Wo, WoT, 2048, 2048);
  gemm256<1><<<dim3(16, 8), 512, 0, stream>>>(qbuf, WoT, d_out, nullptr, 2048);
}

// Round 5
// 343.940 us; speedup vs baseline: 1.2684x; 1.0536x over previous
//
#include <hip/hip_runtime.h>
#include <hip/hip_bf16.h>

// GQA fwd: B=2, S=2048, D_IN=2048, H=16, KV=4, Dh=128, GROUP=4, scale=1/16.
// Inputs fp32, output fp32. Intermediates bf16.
// cvt(x)+tcvt(W) -> fused QKV 128^2-tile counted-vmcnt GEMM (full-chip grid)
// -> vectorized rmsrope(q,k) -> vtrans -> MFMA flash attn (R3 structure,
// ctx in-place into qbuf) -> 128^2 out GEMM (f32).

using u16 = unsigned short;
using u32 = unsigned int;

constexpr int Ss  = 2048;
constexpr int Hh  = 16;
constexpr int KVH = 4;

typedef __attribute__((ext_vector_type(8))) short bf16x8;
typedef __attribute__((ext_vector_type(4))) float f32x4;

__device__ inline float b2f(u16 v)  { return __uint_as_float(((u32)v) << 16); }
__device__ inline u16 f2bf(float x) {
  u32 u = __float_as_uint(x);
  return (u16)((u + 0x7fffu + ((u >> 16) & 1u)) >> 16);
}
// packed RNE f32x2 -> bf16x2 (low half = first arg)
__device__ inline u32 cvtpk(float lo, float hi) {
  u32 r;
  asm("v_cvt_pk_bf16_f32 %0, %1, %2" : "=v"(r) : "v"(lo), "v"(hi));
  return r;
}

typedef const __attribute__((address_space(1))) unsigned int gas_u32;
typedef __attribute__((address_space(3))) unsigned int las_u32;
__device__ inline void gl16(const void* g, void* l) {
  __builtin_amdgcn_global_load_lds((gas_u32*)g, (las_u32*)l, 16, 0, 0);
}

// ---------------------------------------------------------------------------
__global__ __launch_bounds__(256) void cvt_bf16(const float* __restrict__ in,
                                                u16* __restrict__ out, int n4) {
  int i = blockIdx.x * 256 + threadIdx.x;
  if (i < n4) {
    float4 f = reinterpret_cast<const float4*>(in)[i];
    ushort4 o;
    o.x = f2bf(f.x); o.y = f2bf(f.y); o.z = f2bf(f.z); o.w = f2bf(f.w);
    reinterpret_cast<ushort4*>(out)[i] = o;
  }
}

// ---------------------------------------------------------------------------
// W [K][N] fp32 -> W^T [N][K] bf16, 64x64 LDS tiles
// ---------------------------------------------------------------------------
__global__ __launch_bounds__(256) void tcvt(const float* __restrict__ in,
                                            u16* __restrict__ out, int N, int K) {
  __shared__ u16 T[64][66];
  const int k0 = blockIdx.x * 64, n0 = blockIdx.y * 64;
  const int c = threadIdx.x & 63, rb = threadIdx.x >> 6;
#pragma unroll
  for (int p = 0; p < 16; p++) {
    int r = p * 4 + rb;
    T[c][r] = f2bf(in[(size_t)(k0 + r) * N + n0 + c]);
  }
  __syncthreads();
#pragma unroll
  for (int p = 0; p < 16; p++) {
    int nr = p * 4 + rb;
    out[(size_t)(n0 + nr) * K + k0 + c] = T[nr][c];
  }
}

// ---------------------------------------------------------------------------
// v half of kv [4096 tok][1024] bf16 -> vT [(b*4+kvh)][128 d][2048 s]
// ---------------------------------------------------------------------------
__global__ __launch_bounds__(256) void vtrans(const u16* __restrict__ kv,
                                              u16* __restrict__ vT) {
  __shared__ u16 T[64][66];
  const int s0 = blockIdx.x * 64, d0 = blockIdx.y * 64, z = blockIdx.z;
  const int b = z >> 2, kvh = z & 3;
  const int c = threadIdx.x & 63, rb = threadIdx.x >> 6;
#pragma unroll
  for (int p = 0; p < 16; p++) {
    int r = p * 4 + rb;
    T[c][r] = kv[(size_t)(b * Ss + s0 + r) * 1024 + 512 + kvh * 128 + d0 + c];
  }
  __syncthreads();
#pragma unroll
  for (int p = 0; p < 16; p++) {
    int dr = p * 4 + rb;
    vT[((size_t)z * 128 + d0 + dr) * Ss + s0 + c] = T[dr][c];
  }
}

// ---------------------------------------------------------------------------
// 128x128-tile GEMM, BK=64, 256 threads (4 waves 2Mx2N, per-wave 64x64).
// C[M x N] = A[M x K](bf16) @ Bt[N x K](bf16)^T.
// Same schedule as R4's gemm256 (counted-vmcnt double-buffer, stage 2 K-tiles
// ahead, vmcnt(8) -- loads span barriers, never drained in steady state),
// shrunk to 64KB LDS -> 2 blocks/CU resident, and full-chip grids
// (QKV 32x24=768, out 32x16=512). Both-sides XOR chunk swizzle (row&7).
// MODE 0: split bf16 output: cols<2048 -> C0 stride 2048 (q), cols>=2048 ->
//         C1 stride 1024 (kv). MODE 1: f32 output C0 stride 2048.
// ---------------------------------------------------------------------------
template <int MODE>
__global__ __launch_bounds__(256, 2) void gemm128(const u16* __restrict__ A,
                                                  const u16* __restrict__ Bt,
                                                  void* __restrict__ C0,
                                                  u16* __restrict__ C1,
                                                  int K) {
  __shared__ u16 As[2][128 * 64];
  __shared__ u16 Bs[2][128 * 64];
  const int t = threadIdx.x;
  const int wid = t >> 6, lane = t & 63;
  const int lrow = lane & 15, quad = lane >> 4;
  const int wm = wid >> 1, wn = wid & 1;  // 2x2 wave grid; per-wave 64 x 64
  const int m0 = blockIdx.x * 128, n0 = blockIdx.y * 128;
  const int sw8 = (lrow & 7) << 3;

  // staging: thread t stages LDS chunk (p*256+t) each p (row = p*32 + (t>>3),
  // chunk t&7); global col-chunk pre-XORed with (row&7); read same XOR.
  const int srow = t >> 3;                      // 0..31 (+p*32)
  const int sco  = ((t & 7) ^ (srow & 7)) * 8;  // swizzled src col (u16)

  f32x4 acc[4][4];
#pragma unroll
  for (int i = 0; i < 4; i++)
#pragma unroll
    for (int j = 0; j < 4; j++) acc[i][j] = (f32x4)0.f;

#define STAGE(buf, k0)                                                     \
  {                                                                        \
    _Pragma("unroll") for (int p = 0; p < 4; p++) {                        \
      gl16(A + (size_t)(m0 + p * 32 + srow) * K + (k0) + sco,              \
           (char*)As[buf] + (p * 256 + t) * 16);                           \
      gl16(Bt + (size_t)(n0 + p * 32 + srow) * K + (k0) + sco,             \
           (char*)Bs[buf] + (p * 256 + t) * 16);                           \
    }                                                                      \
  }

  const int nk = K >> 6;  // 32
  STAGE(0, 0)
  STAGE(1, 64)
  asm volatile("s_waitcnt vmcnt(8)" ::: "memory");  // buf0 complete
  __builtin_amdgcn_s_barrier();
  __builtin_amdgcn_sched_barrier(0);

  for (int kt = 0; kt < nk; ++kt) {
    const int buf = kt & 1;
#pragma unroll
    for (int kc = 0; kc < 2; kc++) {
      bf16x8 af[4], bfr[4];
#pragma unroll
      for (int i = 0; i < 4; i++)
        af[i] = *reinterpret_cast<const bf16x8*>(
            &As[buf][(wm * 64 + i * 16 + lrow) * 64 + (((kc * 4 + quad) << 3) ^ sw8)]);
#pragma unroll
      for (int j = 0; j < 4; j++)
        bfr[j] = *reinterpret_cast<const bf16x8*>(
            &Bs[buf][(wn * 64 + j * 16 + lrow) * 64 + (((kc * 4 + quad) << 3) ^ sw8)]);
      __builtin_amdgcn_s_setprio(1);
#pragma unroll
      for (int i = 0; i < 4; i++)
#pragma unroll
        for (int j = 0; j < 4; j++)
          acc[i][j] =
              __builtin_amdgcn_mfma_f32_16x16x32_bf16(af[i], bfr[j], acc[i][j], 0, 0, 0);
      __builtin_amdgcn_s_setprio(0);
    }
    __builtin_amdgcn_sched_barrier(0);
    __builtin_amdgcn_s_barrier();  // all waves done reading buf
    __builtin_amdgcn_sched_barrier(0);
    if (kt + 2 < nk) {
      STAGE(buf, (kt + 2) * 64)
    }
    if (kt + 1 < nk) {
      if (kt + 2 < nk) {
        asm volatile("s_waitcnt vmcnt(8)" ::: "memory");  // buf kt+1 ready
      } else {
        asm volatile("s_waitcnt vmcnt(0)" ::: "memory");
      }
      __builtin_amdgcn_s_barrier();
      __builtin_amdgcn_sched_barrier(0);
    }
  }
#undef STAGE

  // epilogue
  if (MODE == 0) {
    u16* C;
    int stride, coff;
    if (n0 < 2048) { C = (u16*)C0; stride = 2048; coff = n0; }
    else           { C = C1;       stride = 1024; coff = n0 - 2048; }
#pragma unroll
    for (int i = 0; i < 4; i++)
#pragma unroll
      for (int j = 0; j < 4; j++)
#pragma unroll
        for (int r = 0; r < 4; r++) {
          int row = m0 + wm * 64 + i * 16 + quad * 4 + r;
          int col = coff + wn * 64 + j * 16 + lrow;
          C[(size_t)row * stride + col] = f2bf(acc[i][j][r]);
        }
  } else {
    float* C = (float*)C0;
#pragma unroll
    for (int i = 0; i < 4; i++)
#pragma unroll
      for (int j = 0; j < 4; j++)
#pragma unroll
        for (int r = 0; r < 4; r++) {
          int row = m0 + wm * 64 + i * 16 + quad * 4 + r;
          int col = n0 + wn * 64 + j * 16 + lrow;
          C[(size_t)row * 2048 + col] = acc[i][j][r];
        }
  }
}

// ---------------------------------------------------------------------------
// Fused RMSNorm + RoPE, vectorized (G13): one wave per 128-el vector, lane l
// holds els (2l, 2l+1) as one u32; the RoPE partner (el +-64) lives at lane
// l^32 -> one shfl_xor(32) after scaling. float2 loads for cos/sin/scale,
// cvt_pk packed store. 20 vectors/token: j<16 -> q head j (stride 2048,
// mult 1/16), j>=16 -> k head j-16 in kv buffer (stride 1024).
// ---------------------------------------------------------------------------
__global__ __launch_bounds__(256) void rmsrope2(u16* __restrict__ qbuf,
                                                u16* __restrict__ kvb,
                                                const float* __restrict__ qsc,
                                                const float* __restrict__ ksc,
                                                const float* __restrict__ cosb,
                                                const float* __restrict__ sinb) {
  const int w = threadIdx.x >> 6, lane = threadIdx.x & 63;
  const int vi = blockIdx.x * 4 + w;
  const int tok = vi / 20, j = vi - tok * 20;
  const int s = tok & (Ss - 1);
  const bool isq = j < 16;
  u16* p = isq ? (qbuf + (size_t)tok * 2048 + j * 128)
               : (kvb + (size_t)tok * 1024 + (j - 16) * 128);
  const float* scale = isq ? qsc : ksc;
  const float mult = isq ? 0.0625f : 1.0f;

  u32* p32 = reinterpret_cast<u32*>(p);
  u32 v = p32[lane];
  float e0 = b2f((u16)(v & 0xffff)), e1 = b2f((u16)(v >> 16));
  float ss = e0 * e0 + e1 * e1;
#pragma unroll
  for (int off = 32; off > 0; off >>= 1) ss += __shfl_xor(ss, off);
  float rr = rsqrtf(ss * (1.0f / 128.0f) + 1e-6f);
  float2 sc = reinterpret_cast<const float2*>(scale)[lane];
  float x0 = e0 * rr * sc.x;
  float x1 = e1 * rr * sc.y;
  float px0 = __shfl_xor(x0, 32);
  float px1 = __shfl_xor(x1, 32);
  float2 c  = reinterpret_cast<const float2*>(cosb + s * 128)[lane];
  float2 sn = reinterpret_cast<const float2*>(sinb + s * 128)[lane];
  float sgn = (lane < 32) ? -1.0f : 1.0f;
  float o0 = (x0 * c.x + sgn * px0 * sn.x) * mult;
  float o1 = (x1 * c.y + sgn * px1 * sn.y) * mult;
  p32[lane] = cvtpk(o0, o1);
}

// ---------------------------------------------------------------------------
// MFMA flash attention (causal, GQA). R3 structure: 64-row q-tiles, 2 waves x
// 32 q-rows, 1024 blocks x 128 threads (4 blocks/CU), single-buffered XOR-
// swizzled gl16 staging, lane-local softmax, defer-max (T13), cvt_pk pack,
// transposed PV. ctx written IN-PLACE into qbuf (block-exclusive rows).
// ---------------------------------------------------------------------------
__global__ __launch_bounds__(128, 2) void attn_mfma(const u16* __restrict__ qb,
                                                    const u16* __restrict__ kv,
                                                    const u16* __restrict__ vT,
                                                    u16* __restrict__ ctx) {
  __shared__ u16 Ks[64 * 128];   // [key][d] linear, chunk^=(key&7)
  __shared__ u16 Vs[128 * 64];   // [d][key] linear, chunk^=(d&7)
  __shared__ u16 Ps[2][32 * 40]; // per-wave P chunk [q][key] stride 40
  const int i = blockIdx.x;
  const int kq = i >> 8, jj = i & 255, x = jj >> 5, hb = jj & 31;
  const int qtile = (kq == 0) ? 31 - x : (kq == 1) ? x : (kq == 2) ? 23 - x : 8 + x;
  const int h = hb & 15, b = hb >> 4;
  const int t = threadIdx.x, w = t >> 6, lane = t & 63;
  const int lrow = lane & 15, quad = lane >> 4;
  const int kvh = h >> 2;
  const int qw = qtile * 64 + w * 32;  // wave's first q row

  const u16* kbase = kv + (size_t)b * Ss * 1024 + kvh * 128;   // key stride 1024
  const u16* vbase = vT + (size_t)(b * KVH + kvh) * 128 * Ss;  // + d*Ss + s

  const int kr  = t >> 4;                       // K row 0..7 (+p8*8)
  const int kco = ((t & 15) ^ (kr & 7)) * 8;    // u16 offset within K row
  const int vr  = t >> 3;                       // V row 0..15 (+p8*16)
  const int vco = ((t & 7) ^ (vr & 7)) * 8;     // u16 offset within V row
  const int sw8 = (lrow & 7) << 3;              // read-side XOR (u16 units)

  // stationary Q B-frags: qf[g][c] -> Q[qw+g*16+lrow][c*32+quad*8 ..+7]
  bf16x8 qf[2][4];
#pragma unroll
  for (int g = 0; g < 2; g++)
#pragma unroll
    for (int c = 0; c < 4; c++)
      qf[g][c] = *reinterpret_cast<const bf16x8*>(
          qb + ((size_t)(b * Ss + qw + g * 16 + lrow) * Hh + h) * 128 + c * 32 + quad * 8);

  f32x4 o[2][8];  // o[g][n]: d = n*16+quad*4+r, q = qw+g*16+lrow
#pragma unroll
  for (int g = 0; g < 2; g++)
#pragma unroll
    for (int n = 0; n < 8; n++) o[g][n] = (f32x4)0.f;
  float mx[2] = {-1e30f, -1e30f}, ls[2] = {0.f, 0.f};

  const int ntile = qtile + 1;
  for (int kt = 0; kt < ntile; kt++) {
    const int kb0 = kt * 64;
    __syncthreads();  // all waves done reading previous tile's LDS
#pragma unroll
    for (int p8 = 0; p8 < 8; p8++) {
      gl16(kbase + (size_t)(kb0 + p8 * 8 + kr) * 1024 + kco,
           (char*)Ks + (p8 * 128 + t) * 16);
      gl16(vbase + (size_t)(p8 * 16 + vr) * Ss + kb0 + vco,
           (char*)Vs + (p8 * 128 + t) * 16);
    }
    __syncthreads();  // implicit vmcnt(0): staged tile ready

    // S^T[key][q]: st[g][mt], key = kb0+mt*16+quad*4+r, q = qw+g*16+lrow
    f32x4 st[2][4];
#pragma unroll
    for (int g = 0; g < 2; g++)
#pragma unroll
      for (int mt = 0; mt < 4; mt++) st[g][mt] = (f32x4)0.f;
#pragma unroll
    for (int c = 0; c < 4; c++) {
      bf16x8 kf[4];
#pragma unroll
      for (int mt = 0; mt < 4; mt++)
        kf[mt] = *reinterpret_cast<const bf16x8*>(
            &Ks[(mt * 16 + lrow) * 128 + ((((c * 4 + quad) << 3)) ^ sw8)]);
      __builtin_amdgcn_s_setprio(1);
#pragma unroll
      for (int mt = 0; mt < 4; mt++)
#pragma unroll
        for (int g = 0; g < 2; g++)
          st[g][mt] =
              __builtin_amdgcn_mfma_f32_16x16x32_bf16(kf[mt], qf[g][c], st[g][mt], 0, 0, 0);
      __builtin_amdgcn_s_setprio(0);
    }
    // causal mask (only the diagonal tile)
    if (kb0 + 63 > qw) {
#pragma unroll
      for (int g = 0; g < 2; g++) {
        int qg = qw + g * 16 + lrow;
#pragma unroll
        for (int mt = 0; mt < 4; mt++) {
          int kg = kb0 + mt * 16 + quad * 4;
#pragma unroll
          for (int r = 0; r < 4; r++)
            st[g][mt][r] = (kg + r > qg) ? -1e30f : st[g][mt][r];
        }
      }
    }
    // online softmax, lane-local state (q = lrow, replicated over quads)
    float tmv[2];
#pragma unroll
    for (int g = 0; g < 2; g++) {
      f32x4 m4;
#pragma unroll
      for (int r = 0; r < 4; r++)
        m4[r] = fmaxf(fmaxf(st[g][0][r], st[g][1][r]), fmaxf(st[g][2][r], st[g][3][r]));
      float tm = fmaxf(fmaxf(m4[0], m4[1]), fmaxf(m4[2], m4[3]));
      tm = fmaxf(tm, __shfl_xor(tm, 16));
      tm = fmaxf(tm, __shfl_xor(tm, 32));
      tmv[g] = tm;
    }
    // defer-max (T13): rescale only if some row grew its max by >8.
    if (__any((tmv[0] > mx[0] + 8.0f) || (tmv[1] > mx[1] + 8.0f))) {
#pragma unroll
      for (int g = 0; g < 2; g++) {
        float mn = fmaxf(mx[g], tmv[g]);
        float a = __expf(mx[g] - mn);
        mx[g] = mn;
        ls[g] *= a;
#pragma unroll
        for (int n = 0; n < 8; n++) o[g][n] *= a;
      }
    }
#pragma unroll
    for (int g = 0; g < 2; g++) {
      float tsum = 0.f;
#pragma unroll
      for (int mt = 0; mt < 4; mt++)
#pragma unroll
        for (int r = 0; r < 4; r++) {
          float pv = __expf(st[g][mt][r] - mx[g]);
          st[g][mt][r] = pv;
          tsum += pv;
        }
      tsum += __shfl_xor(tsum, 16);
      tsum += __shfl_xor(tsum, 32);
      ls[g] += tsum;
    }
    // PV in 2 key-chunks of 32: pack P (cvt_pk) -> per-wave LDS -> B-frag
#pragma unroll
    for (int c2 = 0; c2 < 2; c2++) {
#pragma unroll
      for (int g = 0; g < 2; g++)
#pragma unroll
        for (int mh = 0; mh < 2; mh++) {
          const f32x4 sv = st[g][c2 * 2 + mh];
          uint2 pk;
          pk.x = cvtpk(sv[0], sv[1]);
          pk.y = cvtpk(sv[2], sv[3]);
          *reinterpret_cast<uint2*>(
              &Ps[w][(g * 16 + lrow) * 40 + mh * 16 + quad * 4]) = pk;
        }
      bf16x8 pfr[2];
#pragma unroll
      for (int g = 0; g < 2; g++)
        pfr[g] = *reinterpret_cast<const bf16x8*>(
            &Ps[w][(g * 16 + lrow) * 40 + quad * 8]);
      __builtin_amdgcn_s_setprio(1);
#pragma unroll
      for (int n = 0; n < 8; n++) {
        bf16x8 vf = *reinterpret_cast<const bf16x8*>(
            &Vs[(n * 16 + lrow) * 64 + ((((c2 * 4 + quad) << 3)) ^ sw8)]);
#pragma unroll
        for (int g = 0; g < 2; g++)
          o[g][n] = __builtin_amdgcn_mfma_f32_16x16x32_bf16(vf, pfr[g], o[g][n], 0, 0, 0);
      }
      __builtin_amdgcn_s_setprio(0);
    }
  }

  // epilogue: divide by l (lane-local), packed bf16 store
#pragma unroll
  for (int g = 0; g < 2; g++) {
    float linv = 1.0f / ls[g];
    u16* obase = ctx + ((size_t)(b * Ss + qw + g * 16 + lrow) * Hh + h) * 128 + quad * 4;
#pragma unroll
    for (int n = 0; n < 8; n++) {
      uint2 pk;
      pk.x = cvtpk(o[g][n][0] * linv, o[g][n][1] * linv);
      pk.y = cvtpk(o[g][n][2] * linv, o[g][n][3] * linv);
      *reinterpret_cast<uint2*>(obase + n * 16) = pk;
    }
  }
}

// ---------------------------------------------------------------------------
extern "C" void kernel_launch(void* const* d_in, const int* in_sizes, int n_in,
                              void* d_out, int out_size, void* d_ws, size_t ws_size,
                              hipStream_t stream) {
  const float* x    = (const float*)d_in[0];
  // d_in[1] = mask (unused; causal handled analytically)
  const float* cosb = (const float*)d_in[2];
  const float* sinb = (const float*)d_in[3];
  const float* Wq   = (const float*)d_in[4];
  const float* Wk   = (const float*)d_in[5];
  const float* Wv   = (const float*)d_in[6];
  const float* Wo   = (const float*)d_in[7];
  const float* qsc  = (const float*)d_in[8];
  const float* ksc  = (const float*)d_in[9];

  const int M = 2 * Ss;  // 4096 tokens
  // workspace (u16 elems):
  // xb    [0        .. 8388608)   x bf16 [4096][2048]; dead after QKV gemm
  // Wqkv  [8388608  .. 14680064)  W^T [3072][2048]; dead after QKV gemm
  // qbuf  [14680064 .. 23068672)  q [tok][16][128]; ctx written in-place
  // kvb   [23068672 .. 27262976)  k|v [tok][1024]
  // vTb   = alias of xb[0..2097152)   (used from vtrans onward)
  // WoT   = alias of Wqkv[0..4194304) (used from tcvt(Wo) onward)
  u16* xb   = (u16*)d_ws;
  u16* Wqkv = xb + (size_t)8388608;
  u16* qbuf = Wqkv + (size_t)6291456;
  u16* kvb  = qbuf + (size_t)8388608;
  u16* vTb  = xb;
  u16* WoT  = Wqkv;

  cvt_bf16<<<8192, 256, 0, stream>>>(x, xb, 2097152);

  tcvt<<<dim3(32, 32), 256, 0, stream>>>(Wq, Wqkv, 2048, 2048);
  tcvt<<<dim3(32, 8), 256, 0, stream>>>(Wk, Wqkv + (size_t)2048 * 2048, 512, 2048);
  tcvt<<<dim3(32, 8), 256, 0, stream>>>(Wv, Wqkv + (size_t)2560 * 2048, 512, 2048);

  // fused QKV projection: [4096][3072] split into qbuf (cols<2048) / kvb
  gemm128<0><<<dim3(32, 24), 256, 0, stream>>>(xb, Wqkv, qbuf, kvb, 2048);

  rmsrope2<<<(M * 20) / 4, 256, 0, stream>>>(qbuf, kvb, qsc, ksc, cosb, sinb);

  vtrans<<<dim3(32, 2, 8), 256, 0, stream>>>(kvb, vTb);

  attn_mfma<<<dim3(1024), 128, 0, stream>>>(qbuf, kvb, vTb, qbuf /*in-place*/);

  tcvt<<<dim3(32, 32), 256, 0, stream>>>(Wo, WoT, 2048, 2048);
  gemm128<1><<<dim3(32, 16), 256, 0, stream>>>(qbuf, WoT, d_out, nullptr, 2048);
}